// Round 1
// baseline (10370.826 us; speedup 1.0000x reference)
//
#include <hip/hip_runtime.h>
#include <hip/hip_bf16.h>

#define NN      50000
#define NE      800000
#define ETOT    850000
#define NG      256
#define HC      256

__device__ inline float lrelu(float v) { return v > 0.f ? v : 0.2f * v; }

__device__ inline void atomicMaxF(float* addr, float val) {
    if (val >= 0.f) atomicMax((int*)addr, __float_as_int(val));
    else            atomicMin((unsigned int*)addr, __float_as_uint(val));
}

// h = x @ W  (one node per block, 256 threads = 256 out channels)
// also al_src[n,h] = sum_c h[n,h,c]*asrc[h,c], al_dst likewise.
__global__ void gemm_h_kernel(const float* __restrict__ x, const float* __restrict__ W,
                              const float* __restrict__ asrc, const float* __restrict__ adst,
                              float* __restrict__ h, float* __restrict__ alsrc,
                              float* __restrict__ aldst, int K) {
    int n = blockIdx.x;
    int j = threadIdx.x;
    extern __shared__ float lds[];           // K + 256 floats
    float* xrow = lds;
    float* hrow = lds + K;
    for (int k = j; k < K; k += 256) xrow[k] = x[(size_t)n * K + k];
    __syncthreads();
    float acc = 0.f;
    if (K == 256) {
#pragma unroll 8
        for (int k = 0; k < 256; ++k) acc = fmaf(xrow[k], W[k * 256 + j], acc);
    } else {
        for (int k = 0; k < K; ++k) acc = fmaf(xrow[k], W[k * 256 + j], acc);
    }
    h[(size_t)n * 256 + j] = acc;
    hrow[j] = acc;
    __syncthreads();
    if (j < 8) {
        int hd = j & 3;
        bool is_dst = j >= 4;
        const float* a = is_dst ? adst : asrc;
        float s = 0.f;
        for (int c = 0; c < 64; ++c) s = fmaf(hrow[hd * 64 + c], a[hd * 64 + c], s);
        (is_dst ? aldst : alsrc)[n * 4 + hd] = s;
    }
}

__global__ void init_emax_kernel(float* __restrict__ emax, int n) {
    int t = blockIdx.x * 256 + threadIdx.x;
    if (t < n) emax[t] = -INFINITY;
}

// per (edge, head): atomic max of leaky_relu(al_src[s]+al_dst[d]) into emax[d,h]
__global__ void edge_max_kernel(const int* __restrict__ ei, const float* __restrict__ alsrc,
                                const float* __restrict__ aldst, float* __restrict__ emax) {
    int t = blockIdx.x * 256 + threadIdx.x;
    if (t >= ETOT * 4) return;
    int e = t >> 2, hd = t & 3;
    int s, d;
    if (e < NE) { s = ei[e]; d = ei[NE + e]; } else { s = d = e - NE; }
    float v = lrelu(alsrc[s * 4 + hd] + aldst[d * 4 + hd]);
    atomicMaxF(&emax[d * 4 + hd], v);
}

// per (edge, 4-channel group): agg[d, c] += e * h[s, c];  denom[d, h] += e
__global__ void edge_acc_kernel(const int* __restrict__ ei, const float* __restrict__ alsrc,
                                const float* __restrict__ aldst, const float* __restrict__ emax,
                                const float* __restrict__ h, float* __restrict__ agg,
                                float* __restrict__ denom) {
    long long t = (long long)blockIdx.x * 256 + threadIdx.x;
    if (t >= (long long)ETOT * 64) return;
    int e = (int)(t >> 6), q = (int)(t & 63);
    int hd = q >> 4;
    int s, d;
    if (e < NE) { s = ei[e]; d = ei[NE + e]; } else { s = d = e - NE; }
    float v = lrelu(alsrc[s * 4 + hd] + aldst[d * 4 + hd]);
    float eh = __expf(v - emax[d * 4 + hd]);
    const float4 hv = *(const float4*)(h + (size_t)s * 256 + q * 4);
    float* ap = agg + (size_t)d * 256 + q * 4;
    atomicAdd(ap + 0, eh * hv.x);
    atomicAdd(ap + 1, eh * hv.y);
    atomicAdd(ap + 2, eh * hv.z);
    atomicAdd(ap + 3, eh * hv.w);
    if ((q & 15) == 0) atomicAdd(&denom[d * 4 + hd], eh);
}

// x1 = agg / (denom + 1e-16) + bias   (in place on agg)
__global__ void norm_bias_kernel(float* __restrict__ agg, const float* __restrict__ denom,
                                 const float* __restrict__ bias) {
    int n = blockIdx.x, j = threadIdx.x;
    float dnm = denom[n * 4 + (j >> 6)] + 1e-16f;
    size_t idx = (size_t)n * 256 + j;
    agg[idx] = agg[idx] / dnm + bias[j];
}

__global__ void bn_sum_kernel(const float* __restrict__ x1, float* __restrict__ S) {
    int j = threadIdx.x, b = blockIdx.x;
    float s = 0.f;
    for (int n = b; n < NN; n += gridDim.x) s += x1[(size_t)n * 256 + j];
    atomicAdd(&S[j], s);
}

__global__ void bn_sumsq_kernel(const float* __restrict__ x1, const float* __restrict__ S,
                                float* __restrict__ S2) {
    int j = threadIdx.x, b = blockIdx.x;
    float mu = S[j] * (1.f / NN);
    float s = 0.f;
    for (int n = b; n < NN; n += gridDim.x) {
        float dlt = x1[(size_t)n * 256 + j] - mu;
        s = fmaf(dlt, dlt, s);
    }
    atomicAdd(&S2[j], s);
}

// BN apply + relu -> xnext ; row softmax -> atomic pool into f[batch[n]]
__global__ void bn_apply_pool_kernel(const float* __restrict__ x1, const float* __restrict__ S,
                                     const float* __restrict__ S2, const float* __restrict__ gamma,
                                     const float* __restrict__ beta, const int* __restrict__ batch,
                                     float* __restrict__ xnext, float* __restrict__ f) {
    int n = blockIdx.x, j = threadIdx.x;
    __shared__ float red[256];
    float mu = S[j] * (1.f / NN);
    float var = S2[j] * (1.f / NN);
    float v = (x1[(size_t)n * 256 + j] - mu) * rsqrtf(var + 1e-5f) * gamma[j] + beta[j];
    v = fmaxf(v, 0.f);
    xnext[(size_t)n * 256 + j] = v;
    red[j] = v;
    __syncthreads();
    for (int s = 128; s > 0; s >>= 1) { if (j < s) red[j] = fmaxf(red[j], red[j + s]); __syncthreads(); }
    float m = red[0];
    __syncthreads();
    float ex = __expf(v - m);
    red[j] = ex;
    __syncthreads();
    for (int s = 128; s > 0; s >>= 1) { if (j < s) red[j] += red[j + s]; __syncthreads(); }
    float sum = red[0];
    atomicAdd(&f[batch[n] * 256 + j], ex / sum);
}

// out[i,j] = (relu?) (A[i,:] @ W[:,j] + b[j])
__global__ void mlp_kernel(const float* __restrict__ A, const float* __restrict__ W,
                           const float* __restrict__ b, float* __restrict__ out, int do_relu) {
    int i = blockIdx.x, j = threadIdx.x;
    __shared__ float row[256];
    row[j] = A[i * 256 + j];
    __syncthreads();
    float acc = b[j];
#pragma unroll 8
    for (int k = 0; k < 256; ++k) acc = fmaf(row[k], W[k * 256 + j], acc);
    if (do_relu) acc = fmaxf(acc, 0.f);
    out[i * 256 + j] = acc;
}

extern "C" void kernel_launch(void* const* d_in, const int* in_sizes, int n_in,
                              void* d_out, int out_size, void* d_ws, size_t ws_size,
                              hipStream_t stream) {
    const float* x0     = (const float*)d_in[0];    // 50000 x 9
    const int*   ei     = (const int*)d_in[1];      // 2 x 800000
    const int*   batch  = (const int*)d_in[2];      // 50000
    const float* W0     = (const float*)d_in[3];    // 9 x 256
    const float* asrc0  = (const float*)d_in[4];    // 4 x 64
    const float* adst0  = (const float*)d_in[5];
    const float* bias0  = (const float*)d_in[6];    // 256
    const float* W12    = (const float*)d_in[7];    // 2 x 256 x 256
    const float* asrc12 = (const float*)d_in[8];    // 2 x 4 x 64
    const float* adst12 = (const float*)d_in[9];
    const float* bias12 = (const float*)d_in[10];   // 2 x 256
    const float* gamma  = (const float*)d_in[11];   // 3 x 256
    const float* beta   = (const float*)d_in[12];
    const float* Wm1    = (const float*)d_in[13];   // 256 x 256
    const float* bm1    = (const float*)d_in[14];
    const float* Wm2    = (const float*)d_in[15];
    const float* bm2    = (const float*)d_in[16];
    float* out = (float*)d_out;

    float* ws = (float*)d_ws;
    const size_t NODE_F = (size_t)NN * 256;         // 12.8M floats
    float* h_buf  = ws;
    float* agg    = h_buf + NODE_F;
    float* xb     = agg + NODE_F;
    float* alsrc  = xb + NODE_F;
    float* aldst  = alsrc + (size_t)NN * 4;
    float* emax   = aldst + (size_t)NN * 4;
    float* denom  = emax + (size_t)NN * 4;
    float* S      = denom + (size_t)NN * 4;
    float* S2     = S + 256;
    float* fpool  = S2 + 256;
    float* g_buf  = fpool + 65536;

    hipMemsetAsync(fpool, 0, 65536 * sizeof(float), stream);

    const float* xin = x0;
    int K = 9;
    for (int l = 0; l < 3; ++l) {
        const float* W  = (l == 0) ? W0    : W12    + (size_t)(l - 1) * 256 * 256;
        const float* as = (l == 0) ? asrc0 : asrc12 + (size_t)(l - 1) * 256;
        const float* ad = (l == 0) ? adst0 : adst12 + (size_t)(l - 1) * 256;
        const float* bs = (l == 0) ? bias0 : bias12 + (size_t)(l - 1) * 256;

        gemm_h_kernel<<<NN, 256, (K + 256) * sizeof(float), stream>>>(
            xin, W, as, ad, h_buf, alsrc, aldst, K);

        hipMemsetAsync(agg, 0, NODE_F * sizeof(float), stream);
        hipMemsetAsync(denom, 0, (size_t)NN * 4 * sizeof(float), stream);
        init_emax_kernel<<<(NN * 4 + 255) / 256, 256, 0, stream>>>(emax, NN * 4);

        edge_max_kernel<<<(ETOT * 4 + 255) / 256, 256, 0, stream>>>(ei, alsrc, aldst, emax);

        long long nacc = (long long)ETOT * 64;
        edge_acc_kernel<<<(int)((nacc + 255) / 256), 256, 0, stream>>>(
            ei, alsrc, aldst, emax, h_buf, agg, denom);

        norm_bias_kernel<<<NN, 256, 0, stream>>>(agg, denom, bs);

        hipMemsetAsync(S, 0, 512 * sizeof(float), stream);
        bn_sum_kernel<<<256, 256, 0, stream>>>(agg, S);
        bn_sumsq_kernel<<<256, 256, 0, stream>>>(agg, S, S2);

        bn_apply_pool_kernel<<<NN, 256, 0, stream>>>(
            agg, S, S2, gamma + l * 256, beta + l * 256, batch, xb, fpool);

        xin = xb;
        K = 256;
    }

    mlp_kernel<<<256, 256, 0, stream>>>(fpool, Wm1, bm1, g_buf, 1);
    mlp_kernel<<<256, 256, 0, stream>>>(g_buf, Wm2, bm2, out, 0);
}

// Round 2
// 2295.288 us; speedup vs baseline: 4.5183x; 4.5183x over previous
//
#include <hip/hip_runtime.h>
#include <hip/hip_bf16.h>

#define NN      50000
#define NE      800000
#define ETOT    850000
#define NG      256
#define HC      256

__device__ inline float lrelu(float v) { return v > 0.f ? v : 0.2f * v; }

// h = x @ W  (one node per block, 256 threads = 256 out channels)
// also al_src[n,h] = sum_c h[n,h,c]*asrc[h,c], al_dst likewise.
__global__ void gemm_h_kernel(const float* __restrict__ x, const float* __restrict__ W,
                              const float* __restrict__ asrc, const float* __restrict__ adst,
                              float* __restrict__ h, float* __restrict__ alsrc,
                              float* __restrict__ aldst, int K) {
    int n = blockIdx.x;
    int j = threadIdx.x;
    extern __shared__ float lds[];           // K + 256 floats
    float* xrow = lds;
    float* hrow = lds + K;
    for (int k = j; k < K; k += 256) xrow[k] = x[(size_t)n * K + k];
    __syncthreads();
    float acc = 0.f;
    if (K == 256) {
#pragma unroll 8
        for (int k = 0; k < 256; ++k) acc = fmaf(xrow[k], W[k * 256 + j], acc);
    } else {
        for (int k = 0; k < K; ++k) acc = fmaf(xrow[k], W[k * 256 + j], acc);
    }
    h[(size_t)n * 256 + j] = acc;
    hrow[j] = acc;
    __syncthreads();
    if (j < 8) {
        int hd = j & 3;
        bool is_dst = j >= 4;
        const float* a = is_dst ? adst : asrc;
        float s = 0.f;
        for (int c = 0; c < 64; ++c) s = fmaf(hrow[hd * 64 + c], a[hd * 64 + c], s);
        (is_dst ? aldst : alsrc)[n * 4 + hd] = s;
    }
}

// ---- CSR build (once per call; dst pattern shared by all 3 layers) ----

__global__ void hist_kernel(const int* __restrict__ ei, int* __restrict__ deg) {
    int t = blockIdx.x * 256 + threadIdx.x;
    if (t >= ETOT) return;
    int d = (t < NE) ? ei[NE + t] : t - NE;
    atomicAdd(&deg[d], 1);
}

// single-block exclusive scan of deg[0..NN) -> rowptr[0..NN]
__global__ void scan_kernel(const int* __restrict__ deg, int* __restrict__ rowptr) {
    const int T = 1024, CHUNK = (NN + T - 1) / T;   // 49
    __shared__ int sums[T];
    int t = threadIdx.x;
    int base = t * CHUNK;
    int s = 0;
    for (int i = 0; i < CHUNK; ++i) {
        int idx = base + i;
        if (idx < NN) s += deg[idx];
    }
    sums[t] = s;
    __syncthreads();
    // Hillis-Steele inclusive scan
    for (int d = 1; d < T; d <<= 1) {
        int v = sums[t];
        int add = (t >= d) ? sums[t - d] : 0;
        __syncthreads();
        sums[t] = v + add;
        __syncthreads();
    }
    int off = sums[t] - s;                           // exclusive offset for this thread
    int run = 0;
    for (int i = 0; i < CHUNK; ++i) {
        int idx = base + i;
        if (idx < NN) {
            rowptr[idx] = off + run;
            run += deg[idx];
        }
    }
    if (t == T - 1) rowptr[NN] = sums[T - 1];
}

__global__ void scatter_kernel(const int* __restrict__ ei, int* __restrict__ cursor,
                               int* __restrict__ esrc) {
    int t = blockIdx.x * 256 + threadIdx.x;
    if (t >= ETOT) return;
    int s, d;
    if (t < NE) { s = ei[t]; d = ei[NE + t]; } else { s = d = t - NE; }
    int pos = atomicAdd(&cursor[d], 1);
    esrc[pos] = s;
}

// ---- fused per-dst aggregation: softmax-max, denom, weighted sum, bias ----
// block = one dst node, 256 threads (wave w handles head w for reductions,
// thread j owns output channel j).
__global__ void agg_csr_kernel(const int* __restrict__ rowptr, const int* __restrict__ esrc,
                               const float* __restrict__ alsrc, const float* __restrict__ aldst,
                               const float* __restrict__ h, const float* __restrict__ bias,
                               float* __restrict__ out) {
    int n = blockIdx.x, j = threadIdx.x;
    int hd = j >> 6;
    int beg = rowptr[n], end = rowptr[n + 1];
    float ad = aldst[n * 4 + hd];
    // pass 1: per-head max over in-edges (one wave per head)
    float m = -INFINITY;
    for (int e = beg + (j & 63); e < end; e += 64) {
        int s = esrc[e];
        m = fmaxf(m, lrelu(alsrc[s * 4 + hd] + ad));
    }
    for (int o = 32; o; o >>= 1) m = fmaxf(m, __shfl_xor(m, o, 64));
    // pass 2: denom
    float den = 0.f;
    for (int e = beg + (j & 63); e < end; e += 64) {
        int s = esrc[e];
        den += __expf(lrelu(alsrc[s * 4 + hd] + ad) - m);
    }
    for (int o = 32; o; o >>= 1) den += __shfl_xor(den, o, 64);
    // pass 3: weighted accumulate, one channel per thread
    float acc = 0.f;
    for (int e = beg; e < end; ++e) {
        int s = esrc[e];
        float eh = __expf(lrelu(alsrc[s * 4 + hd] + ad) - m);
        acc = fmaf(eh, h[(size_t)s * 256 + j], acc);
    }
    out[(size_t)n * 256 + j] = acc / (den + 1e-16f) + bias[j];
}

__global__ void bn_sum_kernel(const float* __restrict__ x1, float* __restrict__ S) {
    int j = threadIdx.x, b = blockIdx.x;
    float s = 0.f;
    for (int n = b; n < NN; n += gridDim.x) s += x1[(size_t)n * 256 + j];
    atomicAdd(&S[j], s);
}

__global__ void bn_sumsq_kernel(const float* __restrict__ x1, const float* __restrict__ S,
                                float* __restrict__ S2) {
    int j = threadIdx.x, b = blockIdx.x;
    float mu = S[j] * (1.f / NN);
    float s = 0.f;
    for (int n = b; n < NN; n += gridDim.x) {
        float dlt = x1[(size_t)n * 256 + j] - mu;
        s = fmaf(dlt, dlt, s);
    }
    atomicAdd(&S2[j], s);
}

// BN apply + relu -> xnext ; row softmax -> atomic pool into f[batch[n]]
__global__ void bn_apply_pool_kernel(const float* __restrict__ x1, const float* __restrict__ S,
                                     const float* __restrict__ S2, const float* __restrict__ gamma,
                                     const float* __restrict__ beta, const int* __restrict__ batch,
                                     float* __restrict__ xnext, float* __restrict__ f) {
    int n = blockIdx.x, j = threadIdx.x;
    __shared__ float red[256];
    float mu = S[j] * (1.f / NN);
    float var = S2[j] * (1.f / NN);
    float v = (x1[(size_t)n * 256 + j] - mu) * rsqrtf(var + 1e-5f) * gamma[j] + beta[j];
    v = fmaxf(v, 0.f);
    xnext[(size_t)n * 256 + j] = v;
    red[j] = v;
    __syncthreads();
    for (int s = 128; s > 0; s >>= 1) { if (j < s) red[j] = fmaxf(red[j], red[j + s]); __syncthreads(); }
    float m = red[0];
    __syncthreads();
    float ex = __expf(v - m);
    red[j] = ex;
    __syncthreads();
    for (int s = 128; s > 0; s >>= 1) { if (j < s) red[j] += red[j + s]; __syncthreads(); }
    float sum = red[0];
    atomicAdd(&f[batch[n] * 256 + j], ex / sum);
}

// out[i,j] = (relu?) (A[i,:] @ W[:,j] + b[j])
__global__ void mlp_kernel(const float* __restrict__ A, const float* __restrict__ W,
                           const float* __restrict__ b, float* __restrict__ out, int do_relu) {
    int i = blockIdx.x, j = threadIdx.x;
    __shared__ float row[256];
    row[j] = A[i * 256 + j];
    __syncthreads();
    float acc = b[j];
#pragma unroll 8
    for (int k = 0; k < 256; ++k) acc = fmaf(row[k], W[k * 256 + j], acc);
    if (do_relu) acc = fmaxf(acc, 0.f);
    out[i * 256 + j] = acc;
}

extern "C" void kernel_launch(void* const* d_in, const int* in_sizes, int n_in,
                              void* d_out, int out_size, void* d_ws, size_t ws_size,
                              hipStream_t stream) {
    const float* x0     = (const float*)d_in[0];    // 50000 x 9
    const int*   ei     = (const int*)d_in[1];      // 2 x 800000
    const int*   batch  = (const int*)d_in[2];      // 50000
    const float* W0     = (const float*)d_in[3];    // 9 x 256
    const float* asrc0  = (const float*)d_in[4];    // 4 x 64
    const float* adst0  = (const float*)d_in[5];
    const float* bias0  = (const float*)d_in[6];    // 256
    const float* W12    = (const float*)d_in[7];    // 2 x 256 x 256
    const float* asrc12 = (const float*)d_in[8];    // 2 x 4 x 64
    const float* adst12 = (const float*)d_in[9];
    const float* bias12 = (const float*)d_in[10];   // 2 x 256
    const float* gamma  = (const float*)d_in[11];   // 3 x 256
    const float* beta   = (const float*)d_in[12];
    const float* Wm1    = (const float*)d_in[13];   // 256 x 256
    const float* bm1    = (const float*)d_in[14];
    const float* Wm2    = (const float*)d_in[15];
    const float* bm2    = (const float*)d_in[16];
    float* out = (float*)d_out;

    float* ws = (float*)d_ws;
    const size_t NODE_F = (size_t)NN * 256;         // 12.8M floats
    float* h_buf  = ws;
    float* x1     = h_buf + NODE_F;
    float* xb     = x1 + NODE_F;
    float* alsrc  = xb + NODE_F;
    float* aldst  = alsrc + (size_t)NN * 4;
    float* S      = aldst + (size_t)NN * 4;
    float* S2     = S + 256;
    float* fpool  = S2 + 256;
    float* g_buf  = fpool + 65536;
    int*   deg    = (int*)(g_buf + 65536);
    int*   rowptr = deg + NN + 1;
    int*   cursor = rowptr + NN + 1;
    int*   esrc   = cursor + NN + 1;

    // ---- build CSR by dst (shared by all layers) ----
    hipMemsetAsync(deg, 0, (NN + 1) * sizeof(int), stream);
    hist_kernel<<<(ETOT + 255) / 256, 256, 0, stream>>>(ei, deg);
    scan_kernel<<<1, 1024, 0, stream>>>(deg, rowptr);
    hipMemcpyAsync(cursor, rowptr, (NN + 1) * sizeof(int), hipMemcpyDeviceToDevice, stream);
    scatter_kernel<<<(ETOT + 255) / 256, 256, 0, stream>>>(ei, cursor, esrc);

    hipMemsetAsync(fpool, 0, 65536 * sizeof(float), stream);

    const float* xin = x0;
    int K = 9;
    for (int l = 0; l < 3; ++l) {
        const float* W  = (l == 0) ? W0    : W12    + (size_t)(l - 1) * 256 * 256;
        const float* as = (l == 0) ? asrc0 : asrc12 + (size_t)(l - 1) * 256;
        const float* ad = (l == 0) ? adst0 : adst12 + (size_t)(l - 1) * 256;
        const float* bs = (l == 0) ? bias0 : bias12 + (size_t)(l - 1) * 256;

        gemm_h_kernel<<<NN, 256, (K + 256) * sizeof(float), stream>>>(
            xin, W, as, ad, h_buf, alsrc, aldst, K);

        agg_csr_kernel<<<NN, 256, 0, stream>>>(rowptr, esrc, alsrc, aldst, h_buf, bs, x1);

        hipMemsetAsync(S, 0, 512 * sizeof(float), stream);
        bn_sum_kernel<<<256, 256, 0, stream>>>(x1, S);
        bn_sumsq_kernel<<<256, 256, 0, stream>>>(x1, S, S2);

        bn_apply_pool_kernel<<<NN, 256, 0, stream>>>(
            x1, S, S2, gamma + l * 256, beta + l * 256, batch, xb, fpool);

        xin = xb;
        K = 256;
    }

    mlp_kernel<<<256, 256, 0, stream>>>(fpool, Wm1, bm1, g_buf, 1);
    mlp_kernel<<<256, 256, 0, stream>>>(g_buf, Wm2, bm2, out, 0);
}

// Round 3
// 1499.357 us; speedup vs baseline: 6.9168x; 1.5308x over previous
//
#include <hip/hip_runtime.h>
#include <hip/hip_bf16.h>

#define NN      50000
#define NE      800000
#define ETOT    850000
#define NG      256
#define HC      256
#define TM      64
#define KS      32

__device__ inline float lrelu(float v) { return v > 0.f ? v : 0.2f * v; }

// ---- layer-0 GEMM (K=9): one node per block ----
__global__ void gemm_h_kernel(const float* __restrict__ x, const float* __restrict__ W,
                              const float* __restrict__ asrc, const float* __restrict__ adst,
                              float* __restrict__ h, float* __restrict__ alsrc,
                              float* __restrict__ aldst, int K) {
    int n = blockIdx.x;
    int j = threadIdx.x;
    extern __shared__ float lds[];
    float* xrow = lds;
    float* hrow = lds + K;
    for (int k = j; k < K; k += 256) xrow[k] = x[(size_t)n * K + k];
    __syncthreads();
    float acc = 0.f;
    for (int k = 0; k < K; ++k) acc = fmaf(xrow[k], W[k * 256 + j], acc);
    h[(size_t)n * 256 + j] = acc;
    hrow[j] = acc;
    __syncthreads();
    if (j < 8) {
        int hd = j & 3;
        bool is_dst = j >= 4;
        const float* a = is_dst ? adst : asrc;
        float s = 0.f;
        for (int c = 0; c < 64; ++c) s = fmaf(hrow[hd * 64 + c], a[hd * 64 + c], s);
        (is_dst ? aldst : alsrc)[n * 4 + hd] = s;
    }
}

// ---- layers 1,2 GEMM (K=256): 64x256 tile, 8x8 micro-tile, fused al epilogue ----
__global__ __launch_bounds__(256, 4) void gemm256_kernel(
    const float* __restrict__ x, const float* __restrict__ W,
    const float* __restrict__ asrc, const float* __restrict__ adst,
    float* __restrict__ h, float* __restrict__ alsrc, float* __restrict__ aldst) {
    __shared__ float Xs[KS][TM];     // transposed: Xs[k][r]
    __shared__ float Ws[KS][256];
    int tid = threadIdx.x;
    int m0 = blockIdx.x * TM;
    int cg = tid & 31, rg = tid >> 5;
    int c0 = cg * 4;                 // cols c0..c0+3 and c0+128..c0+131
    int r0 = rg * 8;                 // rows r0..r0+7

    float acc[8][8];
#pragma unroll
    for (int i = 0; i < 8; ++i)
#pragma unroll
        for (int j2 = 0; j2 < 8; ++j2) acc[i][j2] = 0.f;

    // staging assignment
    int sr = tid >> 2;               // 0..63
    int skq = (tid & 3) * 8;         // 0,8,16,24
    int srow = m0 + sr; if (srow >= NN) srow = NN - 1;
    int wk = tid >> 3;               // 0..31
    int wc = (tid & 7) * 32;

    for (int ks = 0; ks < 256; ks += KS) {
        float4 xa = *(const float4*)(x + (size_t)srow * 256 + ks + skq);
        float4 xbv = *(const float4*)(x + (size_t)srow * 256 + ks + skq + 4);
        Xs[skq + 0][sr] = xa.x;  Xs[skq + 1][sr] = xa.y;
        Xs[skq + 2][sr] = xa.z;  Xs[skq + 3][sr] = xa.w;
        Xs[skq + 4][sr] = xbv.x; Xs[skq + 5][sr] = xbv.y;
        Xs[skq + 6][sr] = xbv.z; Xs[skq + 7][sr] = xbv.w;
#pragma unroll
        for (int i = 0; i < 8; ++i)
            *(float4*)&Ws[wk][wc + i * 4] = *(const float4*)(W + (size_t)(ks + wk) * 256 + wc + i * 4);
        __syncthreads();
#pragma unroll 8
        for (int k = 0; k < KS; ++k) {
            float4 xlo = *(float4*)&Xs[k][r0];
            float4 xhi = *(float4*)&Xs[k][r0 + 4];
            float4 wlo = *(float4*)&Ws[k][c0];
            float4 whi = *(float4*)&Ws[k][c0 + 128];
            float xr[8] = {xlo.x, xlo.y, xlo.z, xlo.w, xhi.x, xhi.y, xhi.z, xhi.w};
            float wv[8] = {wlo.x, wlo.y, wlo.z, wlo.w, whi.x, whi.y, whi.z, whi.w};
#pragma unroll
            for (int i = 0; i < 8; ++i)
#pragma unroll
                for (int j2 = 0; j2 < 8; ++j2)
                    acc[i][j2] = fmaf(xr[i], wv[j2], acc[i][j2]);
        }
        __syncthreads();
    }

    // epilogue: store h, fused attention-logit partials
    int hl = cg >> 4;                // head of lo cols (0/1); hi cols head = hl+2
    int cc = c0 & 63;
    float aS[8], aD[8];
#pragma unroll
    for (int i = 0; i < 4; ++i) {
        aS[i]     = asrc[hl * 64 + cc + i];
        aS[4 + i] = asrc[(hl + 2) * 64 + cc + i];
        aD[i]     = adst[hl * 64 + cc + i];
        aD[4 + i] = adst[(hl + 2) * 64 + cc + i];
    }
#pragma unroll
    for (int r = 0; r < 8; ++r) {
        int row = m0 + r0 + r;
        bool valid = row < NN;
        if (valid) {
            *(float4*)(h + (size_t)row * 256 + c0) =
                make_float4(acc[r][0], acc[r][1], acc[r][2], acc[r][3]);
            *(float4*)(h + (size_t)row * 256 + c0 + 128) =
                make_float4(acc[r][4], acc[r][5], acc[r][6], acc[r][7]);
        }
        float ps_lo = acc[r][0]*aS[0] + acc[r][1]*aS[1] + acc[r][2]*aS[2] + acc[r][3]*aS[3];
        float pd_lo = acc[r][0]*aD[0] + acc[r][1]*aD[1] + acc[r][2]*aD[2] + acc[r][3]*aD[3];
        float ps_hi = acc[r][4]*aS[4] + acc[r][5]*aS[5] + acc[r][6]*aS[6] + acc[r][7]*aS[7];
        float pd_hi = acc[r][4]*aD[4] + acc[r][5]*aD[5] + acc[r][6]*aD[6] + acc[r][7]*aD[7];
#pragma unroll
        for (int o = 1; o < 16; o <<= 1) {
            ps_lo += __shfl_xor(ps_lo, o, 64);
            pd_lo += __shfl_xor(pd_lo, o, 64);
            ps_hi += __shfl_xor(ps_hi, o, 64);
            pd_hi += __shfl_xor(pd_hi, o, 64);
        }
        if (((tid & 15) == 0) && valid) {
            alsrc[row * 4 + hl]     = ps_lo;
            aldst[row * 4 + hl]     = pd_lo;
            alsrc[row * 4 + hl + 2] = ps_hi;
            aldst[row * 4 + hl + 2] = pd_hi;
        }
    }
}

// ---- CSR build ----
__global__ void hist_kernel(const int* __restrict__ ei, int* __restrict__ deg) {
    int t = blockIdx.x * 256 + threadIdx.x;
    if (t >= ETOT) return;
    int d = (t < NE) ? ei[NE + t] : t - NE;
    atomicAdd(&deg[d], 1);
}

__global__ void scan_kernel(const int* __restrict__ deg, int* __restrict__ rowptr) {
    const int T = 1024, CHUNK = (NN + T - 1) / T;
    __shared__ int sums[T];
    int t = threadIdx.x;
    int base = t * CHUNK;
    int s = 0;
    for (int i = 0; i < CHUNK; ++i) {
        int idx = base + i;
        if (idx < NN) s += deg[idx];
    }
    sums[t] = s;
    __syncthreads();
    for (int d = 1; d < T; d <<= 1) {
        int v = sums[t];
        int add = (t >= d) ? sums[t - d] : 0;
        __syncthreads();
        sums[t] = v + add;
        __syncthreads();
    }
    int off = sums[t] - s;
    int run = 0;
    for (int i = 0; i < CHUNK; ++i) {
        int idx = base + i;
        if (idx < NN) {
            rowptr[idx] = off + run;
            run += deg[idx];
        }
    }
    if (t == T - 1) rowptr[NN] = sums[T - 1];
}

__global__ void scatter_kernel(const int* __restrict__ ei, int* __restrict__ cursor,
                               int* __restrict__ esrc) {
    int t = blockIdx.x * 256 + threadIdx.x;
    if (t >= ETOT) return;
    int s, d;
    if (t < NE) { s = ei[t]; d = ei[NE + t]; } else { s = d = t - NE; }
    int pos = atomicAdd(&cursor[d], 1);
    esrc[pos] = s;
}

// ---- fused per-dst aggregation ----
__global__ void agg_csr_kernel(const int* __restrict__ rowptr, const int* __restrict__ esrc,
                               const float* __restrict__ alsrc, const float* __restrict__ aldst,
                               const float* __restrict__ h, const float* __restrict__ bias,
                               float* __restrict__ out) {
    int n = blockIdx.x, j = threadIdx.x;
    int hd = j >> 6;
    int beg = rowptr[n], end = rowptr[n + 1];
    float ad = aldst[n * 4 + hd];
    // single-pass online max + denom (one wave per head)
    float m = -INFINITY, den = 0.f;
    for (int e = beg + (j & 63); e < end; e += 64) {
        int s = esrc[e];
        float v = lrelu(alsrc[s * 4 + hd] + ad);
        if (v > m) { den = den * __expf(m - v) + 1.f; m = v; }
        else den += __expf(v - m);
    }
#pragma unroll
    for (int o = 32; o; o >>= 1) {
        float mo = __shfl_xor(m, o, 64);
        float dn = __shfl_xor(den, o, 64);
        float M = fmaxf(m, mo);
        float t1 = (m > -INFINITY) ? den * __expf(m - M) : 0.f;
        float t2 = (mo > -INFINITY) ? dn * __expf(mo - M) : 0.f;
        den = t1 + t2;
        m = M;
    }
    // weighted accumulate, one channel per thread
    float acc = 0.f;
    for (int e = beg; e < end; ++e) {
        int s = esrc[e];
        float eh = __expf(lrelu(alsrc[s * 4 + hd] + ad) - m);
        acc = fmaf(eh, h[(size_t)s * 256 + j], acc);
    }
    out[(size_t)n * 256 + j] = acc / (den + 1e-16f) + bias[j];
}

// ---- fused BN stats: S = sum x, S2 = sum x^2 ----
__global__ void bn_stats_kernel(const float* __restrict__ x1, float* __restrict__ S,
                                float* __restrict__ S2) {
    int j = threadIdx.x, b = blockIdx.x;
    float s = 0.f, s2 = 0.f;
    for (int n = b; n < NN; n += gridDim.x) {
        float v = x1[(size_t)n * 256 + j];
        s += v;
        s2 = fmaf(v, v, s2);
    }
    atomicAdd(&S[j], s);
    atomicAdd(&S2[j], s2);
}

// BN apply + relu -> xnext ; row softmax -> atomic pool into f[batch[n]]
__global__ void bn_apply_pool_kernel(const float* __restrict__ x1, const float* __restrict__ S,
                                     const float* __restrict__ S2, const float* __restrict__ gamma,
                                     const float* __restrict__ beta, const int* __restrict__ batch,
                                     float* __restrict__ xnext, float* __restrict__ f) {
    int n = blockIdx.x, j = threadIdx.x;
    __shared__ float red[256];
    float mu = S[j] * (1.f / NN);
    float var = fmaxf(S2[j] * (1.f / NN) - mu * mu, 0.f);
    float v = (x1[(size_t)n * 256 + j] - mu) * rsqrtf(var + 1e-5f) * gamma[j] + beta[j];
    v = fmaxf(v, 0.f);
    xnext[(size_t)n * 256 + j] = v;
    red[j] = v;
    __syncthreads();
    for (int s = 128; s > 0; s >>= 1) { if (j < s) red[j] = fmaxf(red[j], red[j + s]); __syncthreads(); }
    float m = red[0];
    __syncthreads();
    float ex = __expf(v - m);
    red[j] = ex;
    __syncthreads();
    for (int s = 128; s > 0; s >>= 1) { if (j < s) red[j] += red[j + s]; __syncthreads(); }
    float sum = red[0];
    atomicAdd(&f[batch[n] * 256 + j], ex / sum);
}

__global__ void mlp_kernel(const float* __restrict__ A, const float* __restrict__ W,
                           const float* __restrict__ b, float* __restrict__ out, int do_relu) {
    int i = blockIdx.x, j = threadIdx.x;
    __shared__ float row[256];
    row[j] = A[i * 256 + j];
    __syncthreads();
    float acc = b[j];
#pragma unroll 8
    for (int k = 0; k < 256; ++k) acc = fmaf(row[k], W[k * 256 + j], acc);
    if (do_relu) acc = fmaxf(acc, 0.f);
    out[i * 256 + j] = acc;
}

extern "C" void kernel_launch(void* const* d_in, const int* in_sizes, int n_in,
                              void* d_out, int out_size, void* d_ws, size_t ws_size,
                              hipStream_t stream) {
    const float* x0     = (const float*)d_in[0];
    const int*   ei     = (const int*)d_in[1];
    const int*   batch  = (const int*)d_in[2];
    const float* W0     = (const float*)d_in[3];
    const float* asrc0  = (const float*)d_in[4];
    const float* adst0  = (const float*)d_in[5];
    const float* bias0  = (const float*)d_in[6];
    const float* W12    = (const float*)d_in[7];
    const float* asrc12 = (const float*)d_in[8];
    const float* adst12 = (const float*)d_in[9];
    const float* bias12 = (const float*)d_in[10];
    const float* gamma  = (const float*)d_in[11];
    const float* beta   = (const float*)d_in[12];
    const float* Wm1    = (const float*)d_in[13];
    const float* bm1    = (const float*)d_in[14];
    const float* Wm2    = (const float*)d_in[15];
    const float* bm2    = (const float*)d_in[16];
    float* out = (float*)d_out;

    float* ws = (float*)d_ws;
    const size_t NODE_F = (size_t)NN * 256;
    float* h_buf  = ws;
    float* x1     = h_buf + NODE_F;
    float* xb     = x1 + NODE_F;
    float* alsrc  = xb + NODE_F;
    float* aldst  = alsrc + (size_t)NN * 4;
    float* S      = aldst + (size_t)NN * 4;
    float* S2     = S + 256;
    float* fpool  = S2 + 256;
    float* g_buf  = fpool + 65536;
    int*   deg    = (int*)(g_buf + 65536);
    int*   rowptr = deg + NN + 1;
    int*   cursor = rowptr + NN + 1;
    int*   esrc   = cursor + NN + 1;

    // CSR by dst (shared by all layers)
    hipMemsetAsync(deg, 0, (NN + 1) * sizeof(int), stream);
    hist_kernel<<<(ETOT + 255) / 256, 256, 0, stream>>>(ei, deg);
    scan_kernel<<<1, 1024, 0, stream>>>(deg, rowptr);
    hipMemcpyAsync(cursor, rowptr, (NN + 1) * sizeof(int), hipMemcpyDeviceToDevice, stream);
    scatter_kernel<<<(ETOT + 255) / 256, 256, 0, stream>>>(ei, cursor, esrc);

    hipMemsetAsync(fpool, 0, 65536 * sizeof(float), stream);

    const float* xin = x0;
    for (int l = 0; l < 3; ++l) {
        const float* W  = (l == 0) ? W0    : W12    + (size_t)(l - 1) * 256 * 256;
        const float* as = (l == 0) ? asrc0 : asrc12 + (size_t)(l - 1) * 256;
        const float* ad = (l == 0) ? adst0 : adst12 + (size_t)(l - 1) * 256;
        const float* bs = (l == 0) ? bias0 : bias12 + (size_t)(l - 1) * 256;

        if (l == 0) {
            gemm_h_kernel<<<NN, 256, (9 + 256) * sizeof(float), stream>>>(
                xin, W, as, ad, h_buf, alsrc, aldst, 9);
        } else {
            gemm256_kernel<<<(NN + TM - 1) / TM, 256, 0, stream>>>(
                xin, W, as, ad, h_buf, alsrc, aldst);
        }

        agg_csr_kernel<<<NN, 256, 0, stream>>>(rowptr, esrc, alsrc, aldst, h_buf, bs, x1);

        hipMemsetAsync(S, 0, 512 * sizeof(float), stream);
        bn_stats_kernel<<<256, 256, 0, stream>>>(x1, S, S2);

        bn_apply_pool_kernel<<<NN, 256, 0, stream>>>(
            x1, S, S2, gamma + l * 256, beta + l * 256, batch, xb, fpool);

        xin = xb;
    }

    mlp_kernel<<<256, 256, 0, stream>>>(fpool, Wm1, bm1, g_buf, 1);
    mlp_kernel<<<256, 256, 0, stream>>>(g_buf, Wm2, bm2, out, 0);
}

// Round 4
// 1191.044 us; speedup vs baseline: 8.7073x; 1.2589x over previous
//
#include <hip/hip_runtime.h>
#include <hip/hip_bf16.h>

#define NN      50000
#define NE      800000
#define ETOT    850000
#define NG      256
#define HC      256
#define TM      64
#define KS      32

__device__ inline float lrelu(float v) { return v > 0.f ? v : 0.2f * v; }

__device__ inline unsigned short f2bf(float f) {          // RNE f32->bf16
    unsigned int u = __float_as_uint(f);
    unsigned int r = (u + 0x7FFFu + ((u >> 16) & 1u)) >> 16;
    return (unsigned short)r;
}
__device__ inline float bf2f(unsigned short u) {
    return __uint_as_float((unsigned int)u << 16);
}

// ---- layer-0 GEMM (K=9): one node per block ----
__global__ void gemm_h_kernel(const float* __restrict__ x, const float* __restrict__ W,
                              const float* __restrict__ asrc, const float* __restrict__ adst,
                              unsigned short* __restrict__ h, float* __restrict__ alsrc,
                              float* __restrict__ aldst, int K) {
    int n = blockIdx.x;
    int j = threadIdx.x;
    extern __shared__ float lds[];
    float* xrow = lds;
    float* hrow = lds + K;
    for (int k = j; k < K; k += 256) xrow[k] = x[(size_t)n * K + k];
    __syncthreads();
    float acc = 0.f;
    for (int k = 0; k < K; ++k) acc = fmaf(xrow[k], W[k * 256 + j], acc);
    h[(size_t)n * 256 + j] = f2bf(acc);
    hrow[j] = acc;
    __syncthreads();
    if (j < 8) {
        int hd = j & 3;
        bool is_dst = j >= 4;
        const float* a = is_dst ? adst : asrc;
        float s = 0.f;
        for (int c = 0; c < 64; ++c) s = fmaf(hrow[hd * 64 + c], a[hd * 64 + c], s);
        (is_dst ? aldst : alsrc)[n * 4 + hd] = s;
    }
}

// ---- layers 1,2 GEMM (K=256): 64x256 tile, 8x8 micro-tile, fused al epilogue ----
__global__ __launch_bounds__(256, 4) void gemm256_kernel(
    const float* __restrict__ x, const float* __restrict__ W,
    const float* __restrict__ asrc, const float* __restrict__ adst,
    unsigned short* __restrict__ h, float* __restrict__ alsrc, float* __restrict__ aldst) {
    __shared__ float Xs[KS][TM];     // transposed: Xs[k][r]
    __shared__ float Ws[KS][256];
    int tid = threadIdx.x;
    int m0 = blockIdx.x * TM;
    int cg = tid & 31, rg = tid >> 5;
    int c0 = cg * 4;                 // cols c0..c0+3 and c0+128..c0+131
    int r0 = rg * 8;                 // rows r0..r0+7

    float acc[8][8];
#pragma unroll
    for (int i = 0; i < 8; ++i)
#pragma unroll
        for (int j2 = 0; j2 < 8; ++j2) acc[i][j2] = 0.f;

    int sr = tid >> 2;               // 0..63
    int skq = (tid & 3) * 8;         // 0,8,16,24
    int srow = m0 + sr; if (srow >= NN) srow = NN - 1;
    int wk = tid >> 3;               // 0..31
    int wc = (tid & 7) * 32;

    for (int ks = 0; ks < 256; ks += KS) {
        float4 xa = *(const float4*)(x + (size_t)srow * 256 + ks + skq);
        float4 xbv = *(const float4*)(x + (size_t)srow * 256 + ks + skq + 4);
        Xs[skq + 0][sr] = xa.x;  Xs[skq + 1][sr] = xa.y;
        Xs[skq + 2][sr] = xa.z;  Xs[skq + 3][sr] = xa.w;
        Xs[skq + 4][sr] = xbv.x; Xs[skq + 5][sr] = xbv.y;
        Xs[skq + 6][sr] = xbv.z; Xs[skq + 7][sr] = xbv.w;
#pragma unroll
        for (int i = 0; i < 8; ++i)
            *(float4*)&Ws[wk][wc + i * 4] = *(const float4*)(W + (size_t)(ks + wk) * 256 + wc + i * 4);
        __syncthreads();
#pragma unroll 8
        for (int k = 0; k < KS; ++k) {
            float4 xlo = *(float4*)&Xs[k][r0];
            float4 xhi = *(float4*)&Xs[k][r0 + 4];
            float4 wlo = *(float4*)&Ws[k][c0];
            float4 whi = *(float4*)&Ws[k][c0 + 128];
            float xr[8] = {xlo.x, xlo.y, xlo.z, xlo.w, xhi.x, xhi.y, xhi.z, xhi.w};
            float wv[8] = {wlo.x, wlo.y, wlo.z, wlo.w, whi.x, whi.y, whi.z, whi.w};
#pragma unroll
            for (int i = 0; i < 8; ++i)
#pragma unroll
                for (int j2 = 0; j2 < 8; ++j2)
                    acc[i][j2] = fmaf(xr[i], wv[j2], acc[i][j2]);
        }
        __syncthreads();
    }

    int hl = cg >> 4;                // head of lo cols (0/1); hi cols head = hl+2
    int cc = c0 & 63;
    float aS[8], aD[8];
#pragma unroll
    for (int i = 0; i < 4; ++i) {
        aS[i]     = asrc[hl * 64 + cc + i];
        aS[4 + i] = asrc[(hl + 2) * 64 + cc + i];
        aD[i]     = adst[hl * 64 + cc + i];
        aD[4 + i] = adst[(hl + 2) * 64 + cc + i];
    }
#pragma unroll
    for (int r = 0; r < 8; ++r) {
        int row = m0 + r0 + r;
        bool valid = row < NN;
        if (valid) {
            unsigned int p0 = (unsigned int)f2bf(acc[r][0]) | ((unsigned int)f2bf(acc[r][1]) << 16);
            unsigned int p1 = (unsigned int)f2bf(acc[r][2]) | ((unsigned int)f2bf(acc[r][3]) << 16);
            unsigned int p2 = (unsigned int)f2bf(acc[r][4]) | ((unsigned int)f2bf(acc[r][5]) << 16);
            unsigned int p3 = (unsigned int)f2bf(acc[r][6]) | ((unsigned int)f2bf(acc[r][7]) << 16);
            *(uint2*)(h + (size_t)row * 256 + c0)       = make_uint2(p0, p1);
            *(uint2*)(h + (size_t)row * 256 + c0 + 128) = make_uint2(p2, p3);
        }
        float ps_lo = acc[r][0]*aS[0] + acc[r][1]*aS[1] + acc[r][2]*aS[2] + acc[r][3]*aS[3];
        float pd_lo = acc[r][0]*aD[0] + acc[r][1]*aD[1] + acc[r][2]*aD[2] + acc[r][3]*aD[3];
        float ps_hi = acc[r][4]*aS[4] + acc[r][5]*aS[5] + acc[r][6]*aS[6] + acc[r][7]*aS[7];
        float pd_hi = acc[r][4]*aD[4] + acc[r][5]*aD[5] + acc[r][6]*aD[6] + acc[r][7]*aD[7];
#pragma unroll
        for (int o = 1; o < 16; o <<= 1) {
            ps_lo += __shfl_xor(ps_lo, o, 64);
            pd_lo += __shfl_xor(pd_lo, o, 64);
            ps_hi += __shfl_xor(ps_hi, o, 64);
            pd_hi += __shfl_xor(pd_hi, o, 64);
        }
        if (((tid & 15) == 0) && valid) {
            alsrc[row * 4 + hl]     = ps_lo;
            aldst[row * 4 + hl]     = pd_lo;
            alsrc[row * 4 + hl + 2] = ps_hi;
            aldst[row * 4 + hl + 2] = pd_hi;
        }
    }
}

// ---- CSR build ----
__global__ void hist_kernel(const int* __restrict__ ei, int* __restrict__ deg) {
    int t = blockIdx.x * 256 + threadIdx.x;
    if (t >= ETOT) return;
    int d = (t < NE) ? ei[NE + t] : t - NE;
    atomicAdd(&deg[d], 1);
}

__global__ void scan_kernel(const int* __restrict__ deg, int* __restrict__ rowptr) {
    const int T = 1024, CHUNK = (NN + T - 1) / T;
    __shared__ int sums[T];
    int t = threadIdx.x;
    int base = t * CHUNK;
    int s = 0;
    for (int i = 0; i < CHUNK; ++i) {
        int idx = base + i;
        if (idx < NN) s += deg[idx];
    }
    sums[t] = s;
    __syncthreads();
    for (int d = 1; d < T; d <<= 1) {
        int v = sums[t];
        int add = (t >= d) ? sums[t - d] : 0;
        __syncthreads();
        sums[t] = v + add;
        __syncthreads();
    }
    int off = sums[t] - s;
    int run = 0;
    for (int i = 0; i < CHUNK; ++i) {
        int idx = base + i;
        if (idx < NN) {
            rowptr[idx] = off + run;
            run += deg[idx];
        }
    }
    if (t == T - 1) rowptr[NN] = sums[T - 1];
}

__global__ void scatter_kernel(const int* __restrict__ ei, int* __restrict__ cursor,
                               int* __restrict__ esrc) {
    int t = blockIdx.x * 256 + threadIdx.x;
    if (t >= ETOT) return;
    int s, d;
    if (t < NE) { s = ei[t]; d = ei[NE + t]; } else { s = d = t - NE; }
    int pos = atomicAdd(&cursor[d], 1);
    esrc[pos] = s;
}

// ---- fused per-dst aggregation, single pass (no max-shift; logits are O(10),
// exp stays far from f32 overflow). Per 64-edge chunk: 256 threads compute the
// 4 per-head exp-weights into LDS once, then all threads accumulate channels. ----
__global__ __launch_bounds__(256, 8) void agg_csr_kernel(
    const int* __restrict__ rowptr, const int* __restrict__ esrc,
    const float* __restrict__ alsrc, const float* __restrict__ aldst,
    const unsigned short* __restrict__ h, const float* __restrict__ bias,
    float* __restrict__ out) {
    int n = blockIdx.x, j = threadIdx.x;
    int w = j >> 6;                       // wave id == head of owned channel j
    __shared__ float adS[4];
    __shared__ float ehs[256];            // [edge_in_chunk][head]
    __shared__ int ssrc[64];
    if (j < 4) adS[j] = aldst[n * 4 + j];
    __syncthreads();
    int beg = rowptr[n], end = rowptr[n + 1];
    float acc = 0.f, den = 0.f;
    for (int cb = beg; cb < end; cb += 64) {
        int c = j >> 2, hd2 = j & 3;
        int e = cb + c;
        if (e < end) {
            int s = esrc[e];
            if (hd2 == 0) ssrc[c] = s;
            ehs[(c << 2) | hd2] = __expf(lrelu(alsrc[s * 4 + hd2] + adS[hd2]));
        }
        __syncthreads();
        int cnt = min(64, end - cb);
#pragma unroll 4
        for (int c2 = 0; c2 < cnt; ++c2) {
            float wgt = ehs[(c2 << 2) | w];
            den += wgt;
            acc = fmaf(wgt, bf2f(h[(size_t)ssrc[c2] * 256 + j]), acc);
        }
        __syncthreads();
    }
    out[(size_t)n * 256 + j] = acc / (den + 1e-16f) + bias[j];
}

// ---- fused BN stats: S = sum x, S2 = sum x^2 ----
__global__ void bn_stats_kernel(const float* __restrict__ x1, float* __restrict__ S,
                                float* __restrict__ S2) {
    int j = threadIdx.x, b = blockIdx.x;
    float s = 0.f, s2 = 0.f;
    for (int n = b; n < NN; n += gridDim.x) {
        float v = x1[(size_t)n * 256 + j];
        s += v;
        s2 = fmaf(v, v, s2);
    }
    atomicAdd(&S[j], s);
    atomicAdd(&S2[j], s2);
}

// BN apply + relu -> xnext ; row softmax -> atomic pool into f[batch[n]]
__global__ void bn_apply_pool_kernel(const float* __restrict__ x1, const float* __restrict__ S,
                                     const float* __restrict__ S2, const float* __restrict__ gamma,
                                     const float* __restrict__ beta, const int* __restrict__ batch,
                                     float* __restrict__ xnext, float* __restrict__ f) {
    int n = blockIdx.x, j = threadIdx.x;
    __shared__ float red[256];
    float mu = S[j] * (1.f / NN);
    float var = fmaxf(S2[j] * (1.f / NN) - mu * mu, 0.f);
    float v = (x1[(size_t)n * 256 + j] - mu) * rsqrtf(var + 1e-5f) * gamma[j] + beta[j];
    v = fmaxf(v, 0.f);
    xnext[(size_t)n * 256 + j] = v;
    red[j] = v;
    __syncthreads();
    for (int s = 128; s > 0; s >>= 1) { if (j < s) red[j] = fmaxf(red[j], red[j + s]); __syncthreads(); }
    float m = red[0];
    __syncthreads();
    float ex = __expf(v - m);
    red[j] = ex;
    __syncthreads();
    for (int s = 128; s > 0; s >>= 1) { if (j < s) red[j] += red[j + s]; __syncthreads(); }
    float sum = red[0];
    atomicAdd(&f[batch[n] * 256 + j], ex / sum);
}

__global__ void mlp_kernel(const float* __restrict__ A, const float* __restrict__ W,
                           const float* __restrict__ b, float* __restrict__ out, int do_relu) {
    int i = blockIdx.x, j = threadIdx.x;
    __shared__ float row[256];
    row[j] = A[i * 256 + j];
    __syncthreads();
    float acc = b[j];
#pragma unroll 8
    for (int k = 0; k < 256; ++k) acc = fmaf(row[k], W[k * 256 + j], acc);
    if (do_relu) acc = fmaxf(acc, 0.f);
    out[i * 256 + j] = acc;
}

extern "C" void kernel_launch(void* const* d_in, const int* in_sizes, int n_in,
                              void* d_out, int out_size, void* d_ws, size_t ws_size,
                              hipStream_t stream) {
    const float* x0     = (const float*)d_in[0];
    const int*   ei     = (const int*)d_in[1];
    const int*   batch  = (const int*)d_in[2];
    const float* W0     = (const float*)d_in[3];
    const float* asrc0  = (const float*)d_in[4];
    const float* adst0  = (const float*)d_in[5];
    const float* bias0  = (const float*)d_in[6];
    const float* W12    = (const float*)d_in[7];
    const float* asrc12 = (const float*)d_in[8];
    const float* adst12 = (const float*)d_in[9];
    const float* bias12 = (const float*)d_in[10];
    const float* gamma  = (const float*)d_in[11];
    const float* beta   = (const float*)d_in[12];
    const float* Wm1    = (const float*)d_in[13];
    const float* bm1    = (const float*)d_in[14];
    const float* Wm2    = (const float*)d_in[15];
    const float* bm2    = (const float*)d_in[16];
    float* out = (float*)d_out;

    float* ws = (float*)d_ws;
    const size_t NODE_F = (size_t)NN * 256;
    unsigned short* h16 = (unsigned short*)ws;          // 25.6 MB (occupies first slot)
    float* x1     = ws + NODE_F;
    float* xb     = x1 + NODE_F;
    float* alsrc  = xb + NODE_F;
    float* aldst  = alsrc + (size_t)NN * 4;
    float* S      = aldst + (size_t)NN * 4;
    float* S2     = S + 256;
    float* fpool  = S2 + 256;
    float* g_buf  = fpool + 65536;
    int*   deg    = (int*)(g_buf + 65536);
    int*   rowptr = deg + NN + 1;
    int*   cursor = rowptr + NN + 1;
    int*   esrc   = cursor + NN + 1;

    // CSR by dst (shared by all layers)
    hipMemsetAsync(deg, 0, (NN + 1) * sizeof(int), stream);
    hist_kernel<<<(ETOT + 255) / 256, 256, 0, stream>>>(ei, deg);
    scan_kernel<<<1, 1024, 0, stream>>>(deg, rowptr);
    hipMemcpyAsync(cursor, rowptr, (NN + 1) * sizeof(int), hipMemcpyDeviceToDevice, stream);
    scatter_kernel<<<(ETOT + 255) / 256, 256, 0, stream>>>(ei, cursor, esrc);

    hipMemsetAsync(fpool, 0, 65536 * sizeof(float), stream);

    const float* xin = x0;
    for (int l = 0; l < 3; ++l) {
        const float* W  = (l == 0) ? W0    : W12    + (size_t)(l - 1) * 256 * 256;
        const float* as = (l == 0) ? asrc0 : asrc12 + (size_t)(l - 1) * 256;
        const float* ad = (l == 0) ? adst0 : adst12 + (size_t)(l - 1) * 256;
        const float* bs = (l == 0) ? bias0 : bias12 + (size_t)(l - 1) * 256;

        if (l == 0) {
            gemm_h_kernel<<<NN, 256, (9 + 256) * sizeof(float), stream>>>(
                xin, W, as, ad, h16, alsrc, aldst, 9);
        } else {
            gemm256_kernel<<<(NN + TM - 1) / TM, 256, 0, stream>>>(
                xin, W, as, ad, h16, alsrc, aldst);
        }

        agg_csr_kernel<<<NN, 256, 0, stream>>>(rowptr, esrc, alsrc, aldst, h16, bs, x1);

        hipMemsetAsync(S, 0, 512 * sizeof(float), stream);
        bn_stats_kernel<<<256, 256, 0, stream>>>(x1, S, S2);

        bn_apply_pool_kernel<<<NN, 256, 0, stream>>>(
            x1, S, S2, gamma + l * 256, beta + l * 256, batch, xb, fpool);

        xin = xb;
    }

    mlp_kernel<<<256, 256, 0, stream>>>(fpool, Wm1, bm1, g_buf, 1);
    mlp_kernel<<<256, 256, 0, stream>>>(g_buf, Wm2, bm2, out, 0);
}

// Round 5
// 1025.020 us; speedup vs baseline: 10.1177x; 1.1620x over previous
//
#include <hip/hip_runtime.h>
#include <hip/hip_bf16.h>

#define NN      50000
#define NE      800000
#define ETOT    850000
#define NG      256
#define HC      256

typedef __attribute__((ext_vector_type(8))) short bf8;
typedef __attribute__((ext_vector_type(4))) float f4;

__device__ inline float lrelu(float v) { return v > 0.f ? v : 0.2f * v; }

__device__ inline unsigned short f2bf(float f) {          // RNE f32->bf16
    unsigned int u = __float_as_uint(f);
    unsigned int r = (u + 0x7FFFu + ((u >> 16) & 1u)) >> 16;
    return (unsigned short)r;
}
__device__ inline float bf2f(unsigned short u) {
    return __uint_as_float((unsigned int)u << 16);
}

// ---- layer-0 GEMM (K=9, f32 in): one node per block ----
__global__ void gemm_h_kernel(const float* __restrict__ x, const float* __restrict__ W,
                              const float* __restrict__ asrc, const float* __restrict__ adst,
                              unsigned short* __restrict__ h, float* __restrict__ alsrc,
                              float* __restrict__ aldst, int K) {
    int n = blockIdx.x;
    int j = threadIdx.x;
    extern __shared__ float lds[];
    float* xrow = lds;
    float* hrow = lds + K;
    for (int k = j; k < K; k += 256) xrow[k] = x[(size_t)n * K + k];
    __syncthreads();
    float acc = 0.f;
    for (int k = 0; k < K; ++k) acc = fmaf(xrow[k], W[k * 256 + j], acc);
    h[(size_t)n * 256 + j] = f2bf(acc);
    hrow[j] = acc;
    __syncthreads();
    if (j < 8) {
        int hd = j & 3;
        bool is_dst = j >= 4;
        const float* a = is_dst ? adst : asrc;
        float s = 0.f;
        for (int c = 0; c < 64; ++c) s = fmaf(hrow[hd * 64 + c], a[hd * 64 + c], s);
        (is_dst ? aldst : alsrc)[n * 4 + hd] = s;
    }
}

// ---- W transpose + bf16 convert: Wt[c][k] = bf16(W[k][c]) ----
__global__ void wt_kernel(const float* __restrict__ W, unsigned short* __restrict__ Wt) {
    int c = blockIdx.x, k = threadIdx.x;
    Wt[c * 256 + k] = f2bf(W[k * 256 + c]);
}

// ---- layers 1,2 GEMM via MFMA bf16. Block: 128x128 tile, 4 waves of 64x64.
// A frag: lane l holds X[row = m0+wr+mi*16+(l&15)][k0 + (l>>4)*8 + 0..7]
// B frag: lane l holds W[k][col = n0+wc+ni*16+(l&15)] = Wt[col][k0+(l>>4)*8+..]
// D frag: lane l reg r -> row (l>>4)*4+r, col l&15 (m89-verified layout). ----
__global__ __launch_bounds__(256) void gemm_mfma_kernel(
    const unsigned short* __restrict__ X, const unsigned short* __restrict__ Wt,
    const float* __restrict__ asrc, const float* __restrict__ adst,
    unsigned short* __restrict__ h, float* __restrict__ alsrc, float* __restrict__ aldst) {
    __shared__ unsigned short hs[128 * 132];          // pad 132: 2-way-max conflicts
    int tid = threadIdx.x;
    int w = tid >> 6, l = tid & 63;
    int m0 = blockIdx.x * 128;
    int n0 = blockIdx.y * 128;
    int wr = (w >> 1) * 64, wc = (w & 1) * 64;
    int lr = l & 15, lk = l >> 4;

    f4 acc[4][4];
#pragma unroll
    for (int mi = 0; mi < 4; ++mi)
#pragma unroll
        for (int ni = 0; ni < 4; ++ni) acc[mi][ni] = (f4)(0.f);

    const unsigned short* arow[4];
#pragma unroll
    for (int mi = 0; mi < 4; ++mi) {
        int row = m0 + wr + mi * 16 + lr;
        if (row >= NN) row = NN - 1;
        arow[mi] = X + (size_t)row * 256 + lk * 8;
    }
    const unsigned short* brow[4];
#pragma unroll
    for (int ni = 0; ni < 4; ++ni)
        brow[ni] = Wt + (size_t)(n0 + wc + ni * 16 + lr) * 256 + lk * 8;

#pragma unroll
    for (int kk = 0; kk < 8; ++kk) {
        bf8 a[4], b[4];
#pragma unroll
        for (int mi = 0; mi < 4; ++mi) a[mi] = *(const bf8*)(arow[mi] + kk * 32);
#pragma unroll
        for (int ni = 0; ni < 4; ++ni) b[ni] = *(const bf8*)(brow[ni] + kk * 32);
#pragma unroll
        for (int mi = 0; mi < 4; ++mi)
#pragma unroll
            for (int ni = 0; ni < 4; ++ni)
                acc[mi][ni] = __builtin_amdgcn_mfma_f32_16x16x32_bf16(
                    a[mi], b[ni], acc[mi][ni], 0, 0, 0);
    }

    // ---- attention-logit epilogue: each wave owns head hd for its 64 rows ----
    int hd = (n0 + wc) >> 6;
    float aSv[4], aDv[4];
#pragma unroll
    for (int ni = 0; ni < 4; ++ni) {
        aSv[ni] = asrc[hd * 64 + ni * 16 + lr];
        aDv[ni] = adst[hd * 64 + ni * 16 + lr];
    }
#pragma unroll
    for (int mi = 0; mi < 4; ++mi) {
#pragma unroll
        for (int r = 0; r < 4; ++r) {
            float ps = 0.f, pd = 0.f;
#pragma unroll
            for (int ni = 0; ni < 4; ++ni) {
                ps = fmaf(acc[mi][ni][r], aSv[ni], ps);
                pd = fmaf(acc[mi][ni][r], aDv[ni], pd);
            }
#pragma unroll
            for (int o = 1; o < 16; o <<= 1) {
                ps += __shfl_xor(ps, o, 64);
                pd += __shfl_xor(pd, o, 64);
            }
            if (lr == 0) {
                int row = m0 + wr + mi * 16 + 4 * lk + r;
                if (row < NN) {
                    alsrc[row * 4 + hd] = ps;
                    aldst[row * 4 + hd] = pd;
                }
            }
        }
    }

    // ---- h store: regs -> LDS (bf16) -> coalesced global ----
#pragma unroll
    for (int mi = 0; mi < 4; ++mi)
#pragma unroll
        for (int ni = 0; ni < 4; ++ni) {
            int C = wc + ni * 16 + lr;
#pragma unroll
            for (int r = 0; r < 4; ++r) {
                int R = wr + mi * 16 + 4 * lk + r;
                hs[R * 132 + C] = f2bf(acc[mi][ni][r]);
            }
        }
    __syncthreads();
    {
        int row = tid >> 1, half = tid & 1;
        int grow = m0 + row;
        if (grow < NN) {
            const unsigned short* src = hs + row * 132 + half * 64;
            unsigned short* dst = h + (size_t)grow * 256 + n0 + half * 64;
#pragma unroll
            for (int i = 0; i < 16; ++i)
                *(uint2*)(dst + i * 4) = *(const uint2*)(src + i * 4);
        }
    }
}

// ---- CSR build ----
__global__ void hist_kernel(const int* __restrict__ ei, int* __restrict__ deg) {
    int t = blockIdx.x * 256 + threadIdx.x;
    if (t >= ETOT) return;
    int d = (t < NE) ? ei[NE + t] : t - NE;
    atomicAdd(&deg[d], 1);
}

__global__ void scan_kernel(const int* __restrict__ deg, int* __restrict__ rowptr) {
    const int T = 1024, CHUNK = (NN + T - 1) / T;
    __shared__ int sums[T];
    int t = threadIdx.x;
    int base = t * CHUNK;
    int s = 0;
    for (int i = 0; i < CHUNK; ++i) {
        int idx = base + i;
        if (idx < NN) s += deg[idx];
    }
    sums[t] = s;
    __syncthreads();
    for (int d = 1; d < T; d <<= 1) {
        int v = sums[t];
        int add = (t >= d) ? sums[t - d] : 0;
        __syncthreads();
        sums[t] = v + add;
        __syncthreads();
    }
    int off = sums[t] - s;
    int run = 0;
    for (int i = 0; i < CHUNK; ++i) {
        int idx = base + i;
        if (idx < NN) {
            rowptr[idx] = off + run;
            run += deg[idx];
        }
    }
    if (t == T - 1) rowptr[NN] = sums[T - 1];
}

__global__ void scatter_kernel(const int* __restrict__ ei, int* __restrict__ cursor,
                               int* __restrict__ esrc) {
    int t = blockIdx.x * 256 + threadIdx.x;
    if (t >= ETOT) return;
    int s, d;
    if (t < NE) { s = ei[t]; d = ei[NE + t]; } else { s = d = t - NE; }
    int pos = atomicAdd(&cursor[d], 1);
    esrc[pos] = s;
}

// ---- fused per-dst aggregation, single pass ----
__global__ __launch_bounds__(256, 8) void agg_csr_kernel(
    const int* __restrict__ rowptr, const int* __restrict__ esrc,
    const float* __restrict__ alsrc, const float* __restrict__ aldst,
    const unsigned short* __restrict__ h, const float* __restrict__ bias,
    float* __restrict__ out) {
    int n = blockIdx.x, j = threadIdx.x;
    int w = j >> 6;
    __shared__ float adS[4];
    __shared__ float ehs[256];
    __shared__ int ssrc[64];
    if (j < 4) adS[j] = aldst[n * 4 + j];
    __syncthreads();
    int beg = rowptr[n], end = rowptr[n + 1];
    float acc = 0.f, den = 0.f;
    for (int cb = beg; cb < end; cb += 64) {
        int c = j >> 2, hd2 = j & 3;
        int e = cb + c;
        if (e < end) {
            int s = esrc[e];
            if (hd2 == 0) ssrc[c] = s;
            ehs[(c << 2) | hd2] = __expf(lrelu(alsrc[s * 4 + hd2] + adS[hd2]));
        }
        __syncthreads();
        int cnt = min(64, end - cb);
#pragma unroll 4
        for (int c2 = 0; c2 < cnt; ++c2) {
            float wgt = ehs[(c2 << 2) | w];
            den += wgt;
            acc = fmaf(wgt, bf2f(h[(size_t)ssrc[c2] * 256 + j]), acc);
        }
        __syncthreads();
    }
    out[(size_t)n * 256 + j] = acc / (den + 1e-16f) + bias[j];
}

// ---- fused BN stats ----
__global__ void bn_stats_kernel(const float* __restrict__ x1, float* __restrict__ S,
                                float* __restrict__ S2) {
    int j = threadIdx.x, b = blockIdx.x;
    float s = 0.f, s2 = 0.f;
    for (int n = b; n < NN; n += gridDim.x) {
        float v = x1[(size_t)n * 256 + j];
        s += v;
        s2 = fmaf(v, v, s2);
    }
    atomicAdd(&S[j], s);
    atomicAdd(&S2[j], s2);
}

// BN apply + relu -> xnext(bf16) ; row softmax -> atomic pool into f[batch[n]]
__global__ void bn_apply_pool_kernel(const float* __restrict__ x1, const float* __restrict__ S,
                                     const float* __restrict__ S2, const float* __restrict__ gamma,
                                     const float* __restrict__ beta, const int* __restrict__ batch,
                                     unsigned short* __restrict__ xnext, float* __restrict__ f) {
    int n = blockIdx.x, j = threadIdx.x;
    __shared__ float red[256];
    float mu = S[j] * (1.f / NN);
    float var = fmaxf(S2[j] * (1.f / NN) - mu * mu, 0.f);
    float v = (x1[(size_t)n * 256 + j] - mu) * rsqrtf(var + 1e-5f) * gamma[j] + beta[j];
    v = fmaxf(v, 0.f);
    xnext[(size_t)n * 256 + j] = f2bf(v);
    red[j] = v;
    __syncthreads();
    for (int s = 128; s > 0; s >>= 1) { if (j < s) red[j] = fmaxf(red[j], red[j + s]); __syncthreads(); }
    float m = red[0];
    __syncthreads();
    float ex = __expf(v - m);
    red[j] = ex;
    __syncthreads();
    for (int s = 128; s > 0; s >>= 1) { if (j < s) red[j] += red[j + s]; __syncthreads(); }
    float sum = red[0];
    atomicAdd(&f[batch[n] * 256 + j], ex / sum);
}

__global__ void mlp_kernel(const float* __restrict__ A, const float* __restrict__ W,
                           const float* __restrict__ b, float* __restrict__ out, int do_relu) {
    int i = blockIdx.x, j = threadIdx.x;
    __shared__ float row[256];
    row[j] = A[i * 256 + j];
    __syncthreads();
    float acc = b[j];
#pragma unroll 8
    for (int k = 0; k < 256; ++k) acc = fmaf(row[k], W[k * 256 + j], acc);
    if (do_relu) acc = fmaxf(acc, 0.f);
    out[i * 256 + j] = acc;
}

extern "C" void kernel_launch(void* const* d_in, const int* in_sizes, int n_in,
                              void* d_out, int out_size, void* d_ws, size_t ws_size,
                              hipStream_t stream) {
    const float* x0     = (const float*)d_in[0];
    const int*   ei     = (const int*)d_in[1];
    const int*   batch  = (const int*)d_in[2];
    const float* W0     = (const float*)d_in[3];
    const float* asrc0  = (const float*)d_in[4];
    const float* adst0  = (const float*)d_in[5];
    const float* bias0  = (const float*)d_in[6];
    const float* W12    = (const float*)d_in[7];
    const float* asrc12 = (const float*)d_in[8];
    const float* adst12 = (const float*)d_in[9];
    const float* bias12 = (const float*)d_in[10];
    const float* gamma  = (const float*)d_in[11];
    const float* beta   = (const float*)d_in[12];
    const float* Wm1    = (const float*)d_in[13];
    const float* bm1    = (const float*)d_in[14];
    const float* Wm2    = (const float*)d_in[15];
    const float* bm2    = (const float*)d_in[16];
    float* out = (float*)d_out;

    float* ws = (float*)d_ws;
    const size_t NODE_F = (size_t)NN * 256;
    unsigned short* h16  = (unsigned short*)ws;                 // NODE_F ushorts
    float*          x1   = ws + NODE_F / 2;                     // NODE_F floats
    unsigned short* xb16 = (unsigned short*)(x1 + NODE_F);      // NODE_F ushorts
    unsigned short* wt   = xb16 + NODE_F;                       // 2*65536 ushorts
    float* alsrc  = (float*)(wt + 2 * 65536);
    float* aldst  = alsrc + (size_t)NN * 4;
    float* S      = aldst + (size_t)NN * 4;
    float* S2     = S + 256;
    float* fpool  = S2 + 256;
    float* g_buf  = fpool + 65536;
    int*   deg    = (int*)(g_buf + 65536);
    int*   rowptr = deg + NN + 1;
    int*   cursor = rowptr + NN + 1;
    int*   esrc   = cursor + NN + 1;

    // CSR by dst (shared by all layers)
    hipMemsetAsync(deg, 0, (NN + 1) * sizeof(int), stream);
    hist_kernel<<<(ETOT + 255) / 256, 256, 0, stream>>>(ei, deg);
    scan_kernel<<<1, 1024, 0, stream>>>(deg, rowptr);
    hipMemcpyAsync(cursor, rowptr, (NN + 1) * sizeof(int), hipMemcpyDeviceToDevice, stream);
    scatter_kernel<<<(ETOT + 255) / 256, 256, 0, stream>>>(ei, cursor, esrc);

    // bf16-transposed weights for layers 1,2
    wt_kernel<<<256, 256, 0, stream>>>(W12, wt);
    wt_kernel<<<256, 256, 0, stream>>>(W12 + 65536, wt + 65536);

    hipMemsetAsync(fpool, 0, 65536 * sizeof(float), stream);

    for (int l = 0; l < 3; ++l) {
        const float* as = (l == 0) ? asrc0 : asrc12 + (size_t)(l - 1) * 256;
        const float* ad = (l == 0) ? adst0 : adst12 + (size_t)(l - 1) * 256;
        const float* bs = (l == 0) ? bias0 : bias12 + (size_t)(l - 1) * 256;

        if (l == 0) {
            gemm_h_kernel<<<NN, 256, (9 + 256) * sizeof(float), stream>>>(
                x0, W0, as, ad, h16, alsrc, aldst, 9);
        } else {
            dim3 grid((NN + 127) / 128, 2);
            gemm_mfma_kernel<<<grid, 256, 0, stream>>>(
                xb16, wt + (size_t)(l - 1) * 65536, as, ad, h16, alsrc, aldst);
        }

        agg_csr_kernel<<<NN, 256, 0, stream>>>(rowptr, esrc, alsrc, aldst, h16, bs, x1);

        hipMemsetAsync(S, 0, 512 * sizeof(float), stream);
        bn_stats_kernel<<<1024, 256, 0, stream>>>(x1, S, S2);

        bn_apply_pool_kernel<<<NN, 256, 0, stream>>>(
            x1, S, S2, gamma + l * 256, beta + l * 256, batch, xb16, fpool);
    }

    mlp_kernel<<<256, 256, 0, stream>>>(fpool, Wm1, bm1, g_buf, 1);
    mlp_kernel<<<256, 256, 0, stream>>>(g_buf, Wm2, bm2, out, 0);
}

// Round 6
// 902.257 us; speedup vs baseline: 11.4943x; 1.1361x over previous
//
#include <hip/hip_runtime.h>
#include <hip/hip_bf16.h>

#define NN      50000
#define NE      800000
#define ETOT    850000
#define NG      256
#define HC      256

typedef __attribute__((ext_vector_type(8))) short bf8;
typedef __attribute__((ext_vector_type(4))) float f4;

__device__ inline float lrelu(float v) { return v > 0.f ? v : 0.2f * v; }

__device__ inline unsigned short f2bf(float f) {          // RNE f32->bf16
    unsigned int u = __float_as_uint(f);
    unsigned int r = (u + 0x7FFFu + ((u >> 16) & 1u)) >> 16;
    return (unsigned short)r;
}
__device__ inline float bf2f(unsigned short u) {
    return __uint_as_float((unsigned int)u << 16);
}

// ---- layer-0 GEMM (K=9, f32 in): one node per block ----
__global__ void gemm_h_kernel(const float* __restrict__ x, const float* __restrict__ W,
                              const float* __restrict__ asrc, const float* __restrict__ adst,
                              unsigned short* __restrict__ h, float* __restrict__ alsrc,
                              float* __restrict__ aldst, int K) {
    int n = blockIdx.x;
    int j = threadIdx.x;
    extern __shared__ float lds[];
    float* xrow = lds;
    float* hrow = lds + K;
    for (int k = j; k < K; k += 256) xrow[k] = x[(size_t)n * K + k];
    __syncthreads();
    float acc = 0.f;
    for (int k = 0; k < K; ++k) acc = fmaf(xrow[k], W[k * 256 + j], acc);
    h[(size_t)n * 256 + j] = f2bf(acc);
    hrow[j] = acc;
    __syncthreads();
    if (j < 8) {
        int hd = j & 3;
        bool is_dst = j >= 4;
        const float* a = is_dst ? adst : asrc;
        float s = 0.f;
        for (int c = 0; c < 64; ++c) s = fmaf(hrow[hd * 64 + c], a[hd * 64 + c], s);
        (is_dst ? aldst : alsrc)[n * 4 + hd] = s;
    }
}

// ---- W transpose + bf16 convert: Wt[c][k] = bf16(W[k][c]) ----
__global__ void wt_kernel(const float* __restrict__ W, unsigned short* __restrict__ Wt) {
    int c = blockIdx.x, k = threadIdx.x;
    Wt[c * 256 + k] = f2bf(W[k * 256 + c]);
}

// ---- layers 1,2 GEMM via MFMA bf16. Block: 128x128 tile, 4 waves of 64x64. ----
__global__ __launch_bounds__(256) void gemm_mfma_kernel(
    const unsigned short* __restrict__ X, const unsigned short* __restrict__ Wt,
    const float* __restrict__ asrc, const float* __restrict__ adst,
    unsigned short* __restrict__ h, float* __restrict__ alsrc, float* __restrict__ aldst) {
    __shared__ unsigned short hs[128 * 132];          // pad 132: 2-way-max conflicts
    int tid = threadIdx.x;
    int w = tid >> 6, l = tid & 63;
    int m0 = blockIdx.x * 128;
    int n0 = blockIdx.y * 128;
    int wr = (w >> 1) * 64, wc = (w & 1) * 64;
    int lr = l & 15, lk = l >> 4;

    f4 acc[4][4];
#pragma unroll
    for (int mi = 0; mi < 4; ++mi)
#pragma unroll
        for (int ni = 0; ni < 4; ++ni) acc[mi][ni] = (f4)(0.f);

    const unsigned short* arow[4];
#pragma unroll
    for (int mi = 0; mi < 4; ++mi) {
        int row = m0 + wr + mi * 16 + lr;
        if (row >= NN) row = NN - 1;
        arow[mi] = X + (size_t)row * 256 + lk * 8;
    }
    const unsigned short* brow[4];
#pragma unroll
    for (int ni = 0; ni < 4; ++ni)
        brow[ni] = Wt + (size_t)(n0 + wc + ni * 16 + lr) * 256 + lk * 8;

#pragma unroll
    for (int kk = 0; kk < 8; ++kk) {
        bf8 a[4], b[4];
#pragma unroll
        for (int mi = 0; mi < 4; ++mi) a[mi] = *(const bf8*)(arow[mi] + kk * 32);
#pragma unroll
        for (int ni = 0; ni < 4; ++ni) b[ni] = *(const bf8*)(brow[ni] + kk * 32);
#pragma unroll
        for (int mi = 0; mi < 4; ++mi)
#pragma unroll
            for (int ni = 0; ni < 4; ++ni)
                acc[mi][ni] = __builtin_amdgcn_mfma_f32_16x16x32_bf16(
                    a[mi], b[ni], acc[mi][ni], 0, 0, 0);
    }

    // ---- attention-logit epilogue: each wave owns head hd for its 64 rows ----
    int hd = (n0 + wc) >> 6;
    float aSv[4], aDv[4];
#pragma unroll
    for (int ni = 0; ni < 4; ++ni) {
        aSv[ni] = asrc[hd * 64 + ni * 16 + lr];
        aDv[ni] = adst[hd * 64 + ni * 16 + lr];
    }
#pragma unroll
    for (int mi = 0; mi < 4; ++mi) {
#pragma unroll
        for (int r = 0; r < 4; ++r) {
            float ps = 0.f, pd = 0.f;
#pragma unroll
            for (int ni = 0; ni < 4; ++ni) {
                ps = fmaf(acc[mi][ni][r], aSv[ni], ps);
                pd = fmaf(acc[mi][ni][r], aDv[ni], pd);
            }
#pragma unroll
            for (int o = 1; o < 16; o <<= 1) {
                ps += __shfl_xor(ps, o, 64);
                pd += __shfl_xor(pd, o, 64);
            }
            if (lr == 0) {
                int row = m0 + wr + mi * 16 + 4 * lk + r;
                if (row < NN) {
                    alsrc[row * 4 + hd] = ps;
                    aldst[row * 4 + hd] = pd;
                }
            }
        }
    }

    // ---- h store: regs -> LDS (bf16) -> coalesced global ----
#pragma unroll
    for (int mi = 0; mi < 4; ++mi)
#pragma unroll
        for (int ni = 0; ni < 4; ++ni) {
            int C = wc + ni * 16 + lr;
#pragma unroll
            for (int r = 0; r < 4; ++r) {
                int R = wr + mi * 16 + 4 * lk + r;
                hs[R * 132 + C] = f2bf(acc[mi][ni][r]);
            }
        }
    __syncthreads();
    {
        int row = tid >> 1, half = tid & 1;
        int grow = m0 + row;
        if (grow < NN) {
            const unsigned short* src = hs + row * 132 + half * 64;
            unsigned short* dst = h + (size_t)grow * 256 + n0 + half * 64;
#pragma unroll
            for (int i = 0; i < 16; ++i)
                *(uint2*)(dst + i * 4) = *(const uint2*)(src + i * 4);
        }
    }
}

// ---- CSR build ----
__global__ void hist_kernel(const int* __restrict__ ei, int* __restrict__ deg) {
    int t = blockIdx.x * 256 + threadIdx.x;
    if (t >= ETOT) return;
    int d = (t < NE) ? ei[NE + t] : t - NE;
    atomicAdd(&deg[d], 1);
}

__global__ void scan_kernel(const int* __restrict__ deg, int* __restrict__ rowptr) {
    const int T = 1024, CHUNK = (NN + T - 1) / T;
    __shared__ int sums[T];
    int t = threadIdx.x;
    int base = t * CHUNK;
    int s = 0;
    for (int i = 0; i < CHUNK; ++i) {
        int idx = base + i;
        if (idx < NN) s += deg[idx];
    }
    sums[t] = s;
    __syncthreads();
    for (int d = 1; d < T; d <<= 1) {
        int v = sums[t];
        int add = (t >= d) ? sums[t - d] : 0;
        __syncthreads();
        sums[t] = v + add;
        __syncthreads();
    }
    int off = sums[t] - s;
    int run = 0;
    for (int i = 0; i < CHUNK; ++i) {
        int idx = base + i;
        if (idx < NN) {
            rowptr[idx] = off + run;
            run += deg[idx];
        }
    }
    if (t == T - 1) rowptr[NN] = sums[T - 1];
}

__global__ void scatter_kernel(const int* __restrict__ ei, int* __restrict__ cursor,
                               int* __restrict__ esrc) {
    int t = blockIdx.x * 256 + threadIdx.x;
    if (t >= ETOT) return;
    int s, d;
    if (t < NE) { s = ei[t]; d = ei[NE + t]; } else { s = d = t - NE; }
    int pos = atomicAdd(&cursor[d], 1);
    esrc[pos] = s;
}

// ---- fused per-dst aggregation: ONE WAVE PER NODE.
// Lane l owns channels 4l..4l+3 (all in head l>>4). Per edge: uniform esrc
// read, broadcast alsrc gather, one exp, one uint2 gather = full 512B row
// per wave-instruction. den accumulated redundantly per lane (identical
// within head group) -> no reduction, no LDS, no syncthreads. ----
__global__ __launch_bounds__(256, 8) void agg_csr_kernel(
    const int* __restrict__ rowptr, const int* __restrict__ esrc,
    const float* __restrict__ alsrc, const float* __restrict__ aldst,
    const unsigned short* __restrict__ h, const float* __restrict__ bias,
    float* __restrict__ out) {
    int l = threadIdx.x & 63;
    int n = blockIdx.x * 4 + (threadIdx.x >> 6);   // NN % 4 == 0
    int hd = l >> 4;
    float ad = aldst[n * 4 + hd];
    float4 bv = *(const float4*)(bias + l * 4);
    int beg = rowptr[n], end = rowptr[n + 1];
    float a0 = 0.f, a1 = 0.f, a2 = 0.f, a3 = 0.f, den = 0.f;
#pragma unroll 4
    for (int e = beg; e < end; ++e) {
        int s = esrc[e];
        float wgt = __expf(lrelu(alsrc[s * 4 + hd] + ad));
        uint2 hv = *(const uint2*)(h + (size_t)s * 256 + l * 4);
        den += wgt;
        a0 = fmaf(wgt, bf2f((unsigned short)hv.x), a0);
        a1 = fmaf(wgt, bf2f((unsigned short)(hv.x >> 16)), a1);
        a2 = fmaf(wgt, bf2f((unsigned short)hv.y), a2);
        a3 = fmaf(wgt, bf2f((unsigned short)(hv.y >> 16)), a3);
    }
    float r = 1.f / (den + 1e-16f);
    *(float4*)(out + (size_t)n * 256 + l * 4) =
        make_float4(fmaf(a0, r, bv.x), fmaf(a1, r, bv.y),
                    fmaf(a2, r, bv.z), fmaf(a3, r, bv.w));
}

// ---- fused BN stats ----
__global__ void bn_stats_kernel(const float* __restrict__ x1, float* __restrict__ S,
                                float* __restrict__ S2) {
    int j = threadIdx.x, b = blockIdx.x;
    float s = 0.f, s2 = 0.f;
    for (int n = b; n < NN; n += gridDim.x) {
        float v = x1[(size_t)n * 256 + j];
        s += v;
        s2 = fmaf(v, v, s2);
    }
    atomicAdd(&S[j], s);
    atomicAdd(&S2[j], s2);
}

// BN apply + relu -> xnext(bf16) ; row softmax -> atomic pool into f[batch[n]]
__global__ void bn_apply_pool_kernel(const float* __restrict__ x1, const float* __restrict__ S,
                                     const float* __restrict__ S2, const float* __restrict__ gamma,
                                     const float* __restrict__ beta, const int* __restrict__ batch,
                                     unsigned short* __restrict__ xnext, float* __restrict__ f) {
    int n = blockIdx.x, j = threadIdx.x;
    __shared__ float red[256];
    float mu = S[j] * (1.f / NN);
    float var = fmaxf(S2[j] * (1.f / NN) - mu * mu, 0.f);
    float v = (x1[(size_t)n * 256 + j] - mu) * rsqrtf(var + 1e-5f) * gamma[j] + beta[j];
    v = fmaxf(v, 0.f);
    xnext[(size_t)n * 256 + j] = f2bf(v);
    red[j] = v;
    __syncthreads();
    for (int s = 128; s > 0; s >>= 1) { if (j < s) red[j] = fmaxf(red[j], red[j + s]); __syncthreads(); }
    float m = red[0];
    __syncthreads();
    float ex = __expf(v - m);
    red[j] = ex;
    __syncthreads();
    for (int s = 128; s > 0; s >>= 1) { if (j < s) red[j] += red[j + s]; __syncthreads(); }
    float sum = red[0];
    atomicAdd(&f[batch[n] * 256 + j], ex / sum);
}

__global__ void mlp_kernel(const float* __restrict__ A, const float* __restrict__ W,
                           const float* __restrict__ b, float* __restrict__ out, int do_relu) {
    int i = blockIdx.x, j = threadIdx.x;
    __shared__ float row[256];
    row[j] = A[i * 256 + j];
    __syncthreads();
    float acc = b[j];
#pragma unroll 8
    for (int k = 0; k < 256; ++k) acc = fmaf(row[k], W[k * 256 + j], acc);
    if (do_relu) acc = fmaxf(acc, 0.f);
    out[i * 256 + j] = acc;
}

extern "C" void kernel_launch(void* const* d_in, const int* in_sizes, int n_in,
                              void* d_out, int out_size, void* d_ws, size_t ws_size,
                              hipStream_t stream) {
    const float* x0     = (const float*)d_in[0];
    const int*   ei     = (const int*)d_in[1];
    const int*   batch  = (const int*)d_in[2];
    const float* W0     = (const float*)d_in[3];
    const float* asrc0  = (const float*)d_in[4];
    const float* adst0  = (const float*)d_in[5];
    const float* bias0  = (const float*)d_in[6];
    const float* W12    = (const float*)d_in[7];
    const float* asrc12 = (const float*)d_in[8];
    const float* adst12 = (const float*)d_in[9];
    const float* bias12 = (const float*)d_in[10];
    const float* gamma  = (const float*)d_in[11];
    const float* beta   = (const float*)d_in[12];
    const float* Wm1    = (const float*)d_in[13];
    const float* bm1    = (const float*)d_in[14];
    const float* Wm2    = (const float*)d_in[15];
    const float* bm2    = (const float*)d_in[16];
    float* out = (float*)d_out;

    float* ws = (float*)d_ws;
    const size_t NODE_F = (size_t)NN * 256;
    unsigned short* h16  = (unsigned short*)ws;                 // NODE_F ushorts
    float*          x1   = ws + NODE_F / 2;                     // NODE_F floats
    unsigned short* xb16 = (unsigned short*)(x1 + NODE_F);      // NODE_F ushorts
    unsigned short* wt   = xb16 + NODE_F;                       // 2*65536 ushorts
    float* alsrc  = (float*)(wt + 2 * 65536);
    float* aldst  = alsrc + (size_t)NN * 4;
    float* S      = aldst + (size_t)NN * 4;
    float* S2     = S + 256;
    float* fpool  = S2 + 256;
    float* g_buf  = fpool + 65536;
    int*   deg    = (int*)(g_buf + 65536);
    int*   rowptr = deg + NN + 1;
    int*   cursor = rowptr + NN + 1;
    int*   esrc   = cursor + NN + 1;

    // CSR by dst (shared by all layers)
    hipMemsetAsync(deg, 0, (NN + 1) * sizeof(int), stream);
    hist_kernel<<<(ETOT + 255) / 256, 256, 0, stream>>>(ei, deg);
    scan_kernel<<<1, 1024, 0, stream>>>(deg, rowptr);
    hipMemcpyAsync(cursor, rowptr, (NN + 1) * sizeof(int), hipMemcpyDeviceToDevice, stream);
    scatter_kernel<<<(ETOT + 255) / 256, 256, 0, stream>>>(ei, cursor, esrc);

    // bf16-transposed weights for layers 1,2
    wt_kernel<<<256, 256, 0, stream>>>(W12, wt);
    wt_kernel<<<256, 256, 0, stream>>>(W12 + 65536, wt + 65536);

    hipMemsetAsync(fpool, 0, 65536 * sizeof(float), stream);

    for (int l = 0; l < 3; ++l) {
        const float* as = (l == 0) ? asrc0 : asrc12 + (size_t)(l - 1) * 256;
        const float* ad = (l == 0) ? adst0 : adst12 + (size_t)(l - 1) * 256;
        const float* bs = (l == 0) ? bias0 : bias12 + (size_t)(l - 1) * 256;

        if (l == 0) {
            gemm_h_kernel<<<NN, 256, (9 + 256) * sizeof(float), stream>>>(
                x0, W0, as, ad, h16, alsrc, aldst, 9);
        } else {
            dim3 grid((NN + 127) / 128, 2);
            gemm_mfma_kernel<<<grid, 256, 0, stream>>>(
                xb16, wt + (size_t)(l - 1) * 65536, as, ad, h16, alsrc, aldst);
        }

        agg_csr_kernel<<<NN / 4, 256, 0, stream>>>(rowptr, esrc, alsrc, aldst, h16, bs, x1);

        hipMemsetAsync(S, 0, 512 * sizeof(float), stream);
        bn_stats_kernel<<<1024, 256, 0, stream>>>(x1, S, S2);

        bn_apply_pool_kernel<<<NN, 256, 0, stream>>>(
            x1, S, S2, gamma + l * 256, beta + l * 256, batch, xb16, fpool);
    }

    mlp_kernel<<<256, 256, 0, stream>>>(fpool, Wm1, bm1, g_buf, 1);
    mlp_kernel<<<256, 256, 0, stream>>>(g_buf, Wm2, bm2, out, 0);
}

// Round 7
// 815.715 us; speedup vs baseline: 12.7138x; 1.1061x over previous
//
#include <hip/hip_runtime.h>
#include <hip/hip_bf16.h>

#define NN      50000
#define NE      800000
#define ETOT    850000
#define NG      256
#define HC      256
#define NBLK    ((NN + 255) / 256)   // 196

typedef __attribute__((ext_vector_type(8))) short bf8;
typedef __attribute__((ext_vector_type(4))) float f4;

__device__ inline float lrelu(float v) { return v > 0.f ? v : 0.2f * v; }

__device__ inline unsigned short f2bf(float f) {          // RNE f32->bf16
    unsigned int u = __float_as_uint(f);
    unsigned int r = (u + 0x7FFFu + ((u >> 16) & 1u)) >> 16;
    return (unsigned short)r;
}
__device__ inline float bf2f(unsigned short u) {
    return __uint_as_float((unsigned int)u << 16);
}

// ---- layer-0 GEMM (K=9, f32 in): one node per block ----
__global__ void gemm_h_kernel(const float* __restrict__ x, const float* __restrict__ W,
                              const float* __restrict__ asrc, const float* __restrict__ adst,
                              unsigned short* __restrict__ h, float* __restrict__ alsrc,
                              float* __restrict__ aldst, int K) {
    int n = blockIdx.x;
    int j = threadIdx.x;
    extern __shared__ float lds[];
    float* xrow = lds;
    float* hrow = lds + K;
    for (int k = j; k < K; k += 256) xrow[k] = x[(size_t)n * K + k];
    __syncthreads();
    float acc = 0.f;
    for (int k = 0; k < K; ++k) acc = fmaf(xrow[k], W[k * 256 + j], acc);
    h[(size_t)n * 256 + j] = f2bf(acc);
    hrow[j] = acc;
    __syncthreads();
    if (j < 8) {
        int hd = j & 3;
        bool is_dst = j >= 4;
        const float* a = is_dst ? adst : asrc;
        float s = 0.f;
        for (int c = 0; c < 64; ++c) s = fmaf(hrow[hd * 64 + c], a[hd * 64 + c], s);
        (is_dst ? aldst : alsrc)[n * 4 + hd] = s;
    }
}

// ---- W transpose + bf16 convert: Wt[c][k] = bf16(W[k][c]) ----
__global__ void wt_kernel(const float* __restrict__ W, unsigned short* __restrict__ Wt) {
    int c = blockIdx.x, k = threadIdx.x;
    Wt[c * 256 + k] = f2bf(W[k * 256 + c]);
}

// ---- layers 1,2 GEMM via MFMA bf16. Block: 128x128 tile, 4 waves of 64x64. ----
__global__ __launch_bounds__(256) void gemm_mfma_kernel(
    const unsigned short* __restrict__ X, const unsigned short* __restrict__ Wt,
    const float* __restrict__ asrc, const float* __restrict__ adst,
    unsigned short* __restrict__ h, float* __restrict__ alsrc, float* __restrict__ aldst) {
    __shared__ unsigned short hs[128 * 132];          // pad 132: 2-way-max conflicts
    int tid = threadIdx.x;
    int w = tid >> 6, l = tid & 63;
    int m0 = blockIdx.x * 128;
    int n0 = blockIdx.y * 128;
    int wr = (w >> 1) * 64, wc = (w & 1) * 64;
    int lr = l & 15, lk = l >> 4;

    f4 acc[4][4];
#pragma unroll
    for (int mi = 0; mi < 4; ++mi)
#pragma unroll
        for (int ni = 0; ni < 4; ++ni) acc[mi][ni] = (f4)(0.f);

    const unsigned short* arow[4];
#pragma unroll
    for (int mi = 0; mi < 4; ++mi) {
        int row = m0 + wr + mi * 16 + lr;
        if (row >= NN) row = NN - 1;
        arow[mi] = X + (size_t)row * 256 + lk * 8;
    }
    const unsigned short* brow[4];
#pragma unroll
    for (int ni = 0; ni < 4; ++ni)
        brow[ni] = Wt + (size_t)(n0 + wc + ni * 16 + lr) * 256 + lk * 8;

#pragma unroll
    for (int kk = 0; kk < 8; ++kk) {
        bf8 a[4], b[4];
#pragma unroll
        for (int mi = 0; mi < 4; ++mi) a[mi] = *(const bf8*)(arow[mi] + kk * 32);
#pragma unroll
        for (int ni = 0; ni < 4; ++ni) b[ni] = *(const bf8*)(brow[ni] + kk * 32);
#pragma unroll
        for (int mi = 0; mi < 4; ++mi)
#pragma unroll
            for (int ni = 0; ni < 4; ++ni)
                acc[mi][ni] = __builtin_amdgcn_mfma_f32_16x16x32_bf16(
                    a[mi], b[ni], acc[mi][ni], 0, 0, 0);
    }

    // ---- attention-logit epilogue: each wave owns head hd for its 64 rows ----
    int hd = (n0 + wc) >> 6;
    float aSv[4], aDv[4];
#pragma unroll
    for (int ni = 0; ni < 4; ++ni) {
        aSv[ni] = asrc[hd * 64 + ni * 16 + lr];
        aDv[ni] = adst[hd * 64 + ni * 16 + lr];
    }
#pragma unroll
    for (int mi = 0; mi < 4; ++mi) {
#pragma unroll
        for (int r = 0; r < 4; ++r) {
            float ps = 0.f, pd = 0.f;
#pragma unroll
            for (int ni = 0; ni < 4; ++ni) {
                ps = fmaf(acc[mi][ni][r], aSv[ni], ps);
                pd = fmaf(acc[mi][ni][r], aDv[ni], pd);
            }
#pragma unroll
            for (int o = 1; o < 16; o <<= 1) {
                ps += __shfl_xor(ps, o, 64);
                pd += __shfl_xor(pd, o, 64);
            }
            if (lr == 0) {
                int row = m0 + wr + mi * 16 + 4 * lk + r;
                if (row < NN) {
                    alsrc[row * 4 + hd] = ps;
                    aldst[row * 4 + hd] = pd;
                }
            }
        }
    }

    // ---- h store: regs -> LDS (bf16) -> coalesced global ----
#pragma unroll
    for (int mi = 0; mi < 4; ++mi)
#pragma unroll
        for (int ni = 0; ni < 4; ++ni) {
            int C = wc + ni * 16 + lr;
#pragma unroll
            for (int r = 0; r < 4; ++r) {
                int R = wr + mi * 16 + 4 * lk + r;
                hs[R * 132 + C] = f2bf(acc[mi][ni][r]);
            }
        }
    __syncthreads();
    {
        int row = tid >> 1, half = tid & 1;
        int grow = m0 + row;
        if (grow < NN) {
            const unsigned short* src = hs + row * 132 + half * 64;
            unsigned short* dst = h + (size_t)grow * 256 + n0 + half * 64;
#pragma unroll
            for (int i = 0; i < 16; ++i)
                *(uint2*)(dst + i * 4) = *(const uint2*)(src + i * 4);
        }
    }
}

// ---- CSR build ----
__global__ void hist_kernel(const int* __restrict__ ei, int* __restrict__ deg) {
    int t = blockIdx.x * 256 + threadIdx.x;
    if (t >= ETOT) return;
    int d = (t < NE) ? ei[NE + t] : t - NE;
    atomicAdd(&deg[d], 1);
}

// ---- 3-stage device-wide exclusive scan of deg -> rowptr ----
__global__ void scan1_kernel(const int* __restrict__ deg, int* __restrict__ bsum) {
    __shared__ int red[256];
    int b = blockIdx.x, t = threadIdx.x;
    int idx = b * 256 + t;
    red[t] = (idx < NN) ? deg[idx] : 0;
    __syncthreads();
    for (int s = 128; s > 0; s >>= 1) { if (t < s) red[t] += red[t + s]; __syncthreads(); }
    if (t == 0) bsum[b] = red[0];
}

__global__ void scan2_kernel(const int* __restrict__ bsum, int* __restrict__ boff,
                             int* __restrict__ rowptr) {
    __shared__ int s[256];
    int t = threadIdx.x;
    int v = (t < NBLK) ? bsum[t] : 0;
    s[t] = v;
    __syncthreads();
    for (int d = 1; d < 256; d <<= 1) {
        int x = s[t];
        int a = (t >= d) ? s[t - d] : 0;
        __syncthreads();
        s[t] = x + a;
        __syncthreads();
    }
    if (t < NBLK) boff[t] = s[t] - v;
    if (t == NBLK - 1) rowptr[NN] = s[t];
}

__global__ void scan3_kernel(const int* __restrict__ deg, const int* __restrict__ boff,
                             int* __restrict__ rowptr) {
    __shared__ int s[256];
    int b = blockIdx.x, t = threadIdx.x;
    int idx = b * 256 + t;
    int v = (idx < NN) ? deg[idx] : 0;
    s[t] = v;
    __syncthreads();
    for (int d = 1; d < 256; d <<= 1) {
        int x = s[t];
        int a = (t >= d) ? s[t - d] : 0;
        __syncthreads();
        s[t] = x + a;
        __syncthreads();
    }
    if (idx < NN) rowptr[idx] = boff[b] + s[t] - v;
}

__global__ void scatter_kernel(const int* __restrict__ ei, int* __restrict__ cursor,
                               int* __restrict__ esrc) {
    int t = blockIdx.x * 256 + threadIdx.x;
    if (t >= ETOT) return;
    int s, d;
    if (t < NE) { s = ei[t]; d = ei[NE + t]; } else { s = d = t - NE; }
    int pos = atomicAdd(&cursor[d], 1);
    esrc[pos] = s;
}

// ---- fused per-dst aggregation: ONE WAVE PER NODE. ----
__global__ __launch_bounds__(256, 8) void agg_csr_kernel(
    const int* __restrict__ rowptr, const int* __restrict__ esrc,
    const float* __restrict__ alsrc, const float* __restrict__ aldst,
    const unsigned short* __restrict__ h, const float* __restrict__ bias,
    float* __restrict__ out) {
    int l = threadIdx.x & 63;
    int n = blockIdx.x * 4 + (threadIdx.x >> 6);   // NN % 4 == 0
    int hd = l >> 4;
    float ad = aldst[n * 4 + hd];
    float4 bv = *(const float4*)(bias + l * 4);
    int beg = rowptr[n], end = rowptr[n + 1];
    float a0 = 0.f, a1 = 0.f, a2 = 0.f, a3 = 0.f, den = 0.f;
#pragma unroll 4
    for (int e = beg; e < end; ++e) {
        int s = esrc[e];
        float wgt = __expf(lrelu(alsrc[s * 4 + hd] + ad));
        uint2 hv = *(const uint2*)(h + (size_t)s * 256 + l * 4);
        den += wgt;
        a0 = fmaf(wgt, bf2f((unsigned short)hv.x), a0);
        a1 = fmaf(wgt, bf2f((unsigned short)(hv.x >> 16)), a1);
        a2 = fmaf(wgt, bf2f((unsigned short)hv.y), a2);
        a3 = fmaf(wgt, bf2f((unsigned short)(hv.y >> 16)), a3);
    }
    float r = 1.f / (den + 1e-16f);
    *(float4*)(out + (size_t)n * 256 + l * 4) =
        make_float4(fmaf(a0, r, bv.x), fmaf(a1, r, bv.y),
                    fmaf(a2, r, bv.z), fmaf(a3, r, bv.w));
}

// ---- fused BN stats ----
__global__ void bn_stats_kernel(const float* __restrict__ x1, float* __restrict__ S,
                                float* __restrict__ S2) {
    int j = threadIdx.x, b = blockIdx.x;
    float s = 0.f, s2 = 0.f;
    for (int n = b; n < NN; n += gridDim.x) {
        float v = x1[(size_t)n * 256 + j];
        s += v;
        s2 = fmaf(v, v, s2);
    }
    atomicAdd(&S[j], s);
    atomicAdd(&S2[j], s2);
}

// BN apply + relu -> xnext(bf16) ; row softmax -> atomic pool into f[batch[n]]
__global__ void bn_apply_pool_kernel(const float* __restrict__ x1, const float* __restrict__ S,
                                     const float* __restrict__ S2, const float* __restrict__ gamma,
                                     const float* __restrict__ beta, const int* __restrict__ batch,
                                     unsigned short* __restrict__ xnext, float* __restrict__ f) {
    int n = blockIdx.x, j = threadIdx.x;
    __shared__ float red[256];
    float mu = S[j] * (1.f / NN);
    float var = fmaxf(S2[j] * (1.f / NN) - mu * mu, 0.f);
    float v = (x1[(size_t)n * 256 + j] - mu) * rsqrtf(var + 1e-5f) * gamma[j] + beta[j];
    v = fmaxf(v, 0.f);
    xnext[(size_t)n * 256 + j] = f2bf(v);
    red[j] = v;
    __syncthreads();
    for (int s = 128; s > 0; s >>= 1) { if (j < s) red[j] = fmaxf(red[j], red[j + s]); __syncthreads(); }
    float m = red[0];
    __syncthreads();
    float ex = __expf(v - m);
    red[j] = ex;
    __syncthreads();
    for (int s = 128; s > 0; s >>= 1) { if (j < s) red[j] += red[j + s]; __syncthreads(); }
    float sum = red[0];
    atomicAdd(&f[batch[n] * 256 + j], ex / sum);
}

__global__ void mlp_kernel(const float* __restrict__ A, const float* __restrict__ W,
                           const float* __restrict__ b, float* __restrict__ out, int do_relu) {
    int i = blockIdx.x, j = threadIdx.x;
    __shared__ float row[256];
    row[j] = A[i * 256 + j];
    __syncthreads();
    float acc = b[j];
#pragma unroll 8
    for (int k = 0; k < 256; ++k) acc = fmaf(row[k], W[k * 256 + j], acc);
    if (do_relu) acc = fmaxf(acc, 0.f);
    out[i * 256 + j] = acc;
}

extern "C" void kernel_launch(void* const* d_in, const int* in_sizes, int n_in,
                              void* d_out, int out_size, void* d_ws, size_t ws_size,
                              hipStream_t stream) {
    const float* x0     = (const float*)d_in[0];
    const int*   ei     = (const int*)d_in[1];
    const int*   batch  = (const int*)d_in[2];
    const float* W0     = (const float*)d_in[3];
    const float* asrc0  = (const float*)d_in[4];
    const float* adst0  = (const float*)d_in[5];
    const float* bias0  = (const float*)d_in[6];
    const float* W12    = (const float*)d_in[7];
    const float* asrc12 = (const float*)d_in[8];
    const float* adst12 = (const float*)d_in[9];
    const float* bias12 = (const float*)d_in[10];
    const float* gamma  = (const float*)d_in[11];
    const float* beta   = (const float*)d_in[12];
    const float* Wm1    = (const float*)d_in[13];
    const float* bm1    = (const float*)d_in[14];
    const float* Wm2    = (const float*)d_in[15];
    const float* bm2    = (const float*)d_in[16];
    float* out = (float*)d_out;

    float* ws = (float*)d_ws;
    const size_t NODE_F = (size_t)NN * 256;
    unsigned short* h16  = (unsigned short*)ws;                 // NODE_F ushorts
    float*          x1   = ws + NODE_F / 2;                     // NODE_F floats
    unsigned short* xb16 = (unsigned short*)(x1 + NODE_F);      // NODE_F ushorts
    unsigned short* wt   = xb16 + NODE_F;                       // 2*65536 ushorts
    float* alsrc  = (float*)(wt + 2 * 65536);
    float* aldst  = alsrc + (size_t)NN * 4;
    float* S      = aldst + (size_t)NN * 4;
    float* S2     = S + 256;
    float* fpool  = S2 + 256;
    float* g_buf  = fpool + 65536;
    int*   deg    = (int*)(g_buf + 65536);
    int*   rowptr = deg + NN + 1;
    int*   cursor = rowptr + NN + 1;
    int*   bsum   = cursor + NN + 1;
    int*   boff   = bsum + NBLK + 1;
    int*   esrc   = boff + NBLK + 1;

    // CSR by dst (shared by all layers)
    hipMemsetAsync(deg, 0, (NN + 1) * sizeof(int), stream);
    hist_kernel<<<(ETOT + 255) / 256, 256, 0, stream>>>(ei, deg);
    scan1_kernel<<<NBLK, 256, 0, stream>>>(deg, bsum);
    scan2_kernel<<<1, 256, 0, stream>>>(bsum, boff, rowptr);
    scan3_kernel<<<NBLK, 256, 0, stream>>>(deg, boff, rowptr);
    hipMemcpyAsync(cursor, rowptr, (NN + 1) * sizeof(int), hipMemcpyDeviceToDevice, stream);
    scatter_kernel<<<(ETOT + 255) / 256, 256, 0, stream>>>(ei, cursor, esrc);

    // bf16-transposed weights for layers 1,2
    wt_kernel<<<256, 256, 0, stream>>>(W12, wt);
    wt_kernel<<<256, 256, 0, stream>>>(W12 + 65536, wt + 65536);

    hipMemsetAsync(fpool, 0, 65536 * sizeof(float), stream);

    for (int l = 0; l < 3; ++l) {
        const float* as = (l == 0) ? asrc0 : asrc12 + (size_t)(l - 1) * 256;
        const float* ad = (l == 0) ? adst0 : adst12 + (size_t)(l - 1) * 256;
        const float* bs = (l == 0) ? bias0 : bias12 + (size_t)(l - 1) * 256;

        if (l == 0) {
            gemm_h_kernel<<<NN, 256, (9 + 256) * sizeof(float), stream>>>(
                x0, W0, as, ad, h16, alsrc, aldst, 9);
        } else {
            dim3 grid((NN + 127) / 128, 2);
            gemm_mfma_kernel<<<grid, 256, 0, stream>>>(
                xb16, wt + (size_t)(l - 1) * 65536, as, ad, h16, alsrc, aldst);
        }

        agg_csr_kernel<<<NN / 4, 256, 0, stream>>>(rowptr, esrc, alsrc, aldst, h16, bs, x1);

        hipMemsetAsync(S, 0, 512 * sizeof(float), stream);
        bn_stats_kernel<<<1024, 256, 0, stream>>>(x1, S, S2);

        bn_apply_pool_kernel<<<NN, 256, 0, stream>>>(
            x1, S, S2, gamma + l * 256, beta + l * 256, batch, xb16, fpool);
    }

    mlp_kernel<<<256, 256, 0, stream>>>(fpool, Wm1, bm1, g_buf, 1);
    mlp_kernel<<<256, 256, 0, stream>>>(g_buf, Wm2, bm2, out, 0);
}

// Round 8
// 714.687 us; speedup vs baseline: 14.5110x; 1.1414x over previous
//
#include <hip/hip_runtime.h>
#include <hip/hip_bf16.h>

#define NN      50000
#define NE      800000
#define ETOT    850000
#define NG      256
#define HC      256
#define NBLK    ((NN + 255) / 256)   // 196

typedef __attribute__((ext_vector_type(8))) short bf8;
typedef __attribute__((ext_vector_type(4))) float f4;

__device__ inline float lrelu(float v) { return v > 0.f ? v : 0.2f * v; }

__device__ inline unsigned short f2bf(float f) {          // RNE f32->bf16
    unsigned int u = __float_as_uint(f);
    unsigned int r = (u + 0x7FFFu + ((u >> 16) & 1u)) >> 16;
    return (unsigned short)r;
}
__device__ inline float bf2f(unsigned short u) {
    return __uint_as_float((unsigned int)u << 16);
}

// ---- layer-0 GEMM (K=9, f32 in): one node per block ----
__global__ void gemm_h_kernel(const float* __restrict__ x, const float* __restrict__ W,
                              const float* __restrict__ asrc, const float* __restrict__ adst,
                              unsigned short* __restrict__ h, float* __restrict__ alsrc,
                              float* __restrict__ aldst, int K) {
    int n = blockIdx.x;
    int j = threadIdx.x;
    extern __shared__ float lds[];
    float* xrow = lds;
    float* hrow = lds + K;
    for (int k = j; k < K; k += 256) xrow[k] = x[(size_t)n * K + k];
    __syncthreads();
    float acc = 0.f;
    for (int k = 0; k < K; ++k) acc = fmaf(xrow[k], W[k * 256 + j], acc);
    h[(size_t)n * 256 + j] = f2bf(acc);
    hrow[j] = acc;
    __syncthreads();
    if (j < 8) {
        int hd = j & 3;
        bool is_dst = j >= 4;
        const float* a = is_dst ? adst : asrc;
        float s = 0.f;
        for (int c = 0; c < 64; ++c) s = fmaf(hrow[hd * 64 + c], a[hd * 64 + c], s);
        (is_dst ? aldst : alsrc)[n * 4 + hd] = s;
    }
}

// ---- W transpose + bf16 convert: Wt[c][k] = bf16(W[k][c]) ----
__global__ void wt_kernel(const float* __restrict__ W, unsigned short* __restrict__ Wt) {
    int c = blockIdx.x, k = threadIdx.x;
    Wt[c * 256 + k] = f2bf(W[k * 256 + c]);
}

// ---- layers 1,2 GEMM via MFMA bf16. Block: 128x128 tile, 4 waves of 64x64. ----
__global__ __launch_bounds__(256) void gemm_mfma_kernel(
    const unsigned short* __restrict__ X, const unsigned short* __restrict__ Wt,
    const float* __restrict__ asrc, const float* __restrict__ adst,
    unsigned short* __restrict__ h, float* __restrict__ alsrc, float* __restrict__ aldst) {
    __shared__ unsigned short hs[128 * 132];          // pad 132: 2-way-max conflicts
    int tid = threadIdx.x;
    int w = tid >> 6, l = tid & 63;
    int m0 = blockIdx.x * 128;
    int n0 = blockIdx.y * 128;
    int wr = (w >> 1) * 64, wc = (w & 1) * 64;
    int lr = l & 15, lk = l >> 4;

    f4 acc[4][4];
#pragma unroll
    for (int mi = 0; mi < 4; ++mi)
#pragma unroll
        for (int ni = 0; ni < 4; ++ni) acc[mi][ni] = (f4)(0.f);

    const unsigned short* arow[4];
#pragma unroll
    for (int mi = 0; mi < 4; ++mi) {
        int row = m0 + wr + mi * 16 + lr;
        if (row >= NN) row = NN - 1;
        arow[mi] = X + (size_t)row * 256 + lk * 8;
    }
    const unsigned short* brow[4];
#pragma unroll
    for (int ni = 0; ni < 4; ++ni)
        brow[ni] = Wt + (size_t)(n0 + wc + ni * 16 + lr) * 256 + lk * 8;

#pragma unroll
    for (int kk = 0; kk < 8; ++kk) {
        bf8 a[4], b[4];
#pragma unroll
        for (int mi = 0; mi < 4; ++mi) a[mi] = *(const bf8*)(arow[mi] + kk * 32);
#pragma unroll
        for (int ni = 0; ni < 4; ++ni) b[ni] = *(const bf8*)(brow[ni] + kk * 32);
#pragma unroll
        for (int mi = 0; mi < 4; ++mi)
#pragma unroll
            for (int ni = 0; ni < 4; ++ni)
                acc[mi][ni] = __builtin_amdgcn_mfma_f32_16x16x32_bf16(
                    a[mi], b[ni], acc[mi][ni], 0, 0, 0);
    }

    // ---- attention-logit epilogue: each wave owns head hd for its 64 rows ----
    int hd = (n0 + wc) >> 6;
    float aSv[4], aDv[4];
#pragma unroll
    for (int ni = 0; ni < 4; ++ni) {
        aSv[ni] = asrc[hd * 64 + ni * 16 + lr];
        aDv[ni] = adst[hd * 64 + ni * 16 + lr];
    }
#pragma unroll
    for (int mi = 0; mi < 4; ++mi) {
#pragma unroll
        for (int r = 0; r < 4; ++r) {
            float ps = 0.f, pd = 0.f;
#pragma unroll
            for (int ni = 0; ni < 4; ++ni) {
                ps = fmaf(acc[mi][ni][r], aSv[ni], ps);
                pd = fmaf(acc[mi][ni][r], aDv[ni], pd);
            }
#pragma unroll
            for (int o = 1; o < 16; o <<= 1) {
                ps += __shfl_xor(ps, o, 64);
                pd += __shfl_xor(pd, o, 64);
            }
            if (lr == 0) {
                int row = m0 + wr + mi * 16 + 4 * lk + r;
                if (row < NN) {
                    alsrc[row * 4 + hd] = ps;
                    aldst[row * 4 + hd] = pd;
                }
            }
        }
    }

    // ---- h store: regs -> LDS (bf16) -> coalesced global ----
#pragma unroll
    for (int mi = 0; mi < 4; ++mi)
#pragma unroll
        for (int ni = 0; ni < 4; ++ni) {
            int C = wc + ni * 16 + lr;
#pragma unroll
            for (int r = 0; r < 4; ++r) {
                int R = wr + mi * 16 + 4 * lk + r;
                hs[R * 132 + C] = f2bf(acc[mi][ni][r]);
            }
        }
    __syncthreads();
    {
        int row = tid >> 1, half = tid & 1;
        int grow = m0 + row;
        if (grow < NN) {
            const unsigned short* src = hs + row * 132 + half * 64;
            unsigned short* dst = h + (size_t)grow * 256 + n0 + half * 64;
#pragma unroll
            for (int i = 0; i < 16; ++i)
                *(uint2*)(dst + i * 4) = *(const uint2*)(src + i * 4);
        }
    }
}

// ---- CSR build ----
__global__ void hist_kernel(const int* __restrict__ ei, int* __restrict__ deg) {
    int t = blockIdx.x * 256 + threadIdx.x;
    if (t >= ETOT) return;
    int d = (t < NE) ? ei[NE + t] : t - NE;
    atomicAdd(&deg[d], 1);
}

// ---- 3-stage device-wide exclusive scan of deg -> rowptr ----
__global__ void scan1_kernel(const int* __restrict__ deg, int* __restrict__ bsum) {
    __shared__ int red[256];
    int b = blockIdx.x, t = threadIdx.x;
    int idx = b * 256 + t;
    red[t] = (idx < NN) ? deg[idx] : 0;
    __syncthreads();
    for (int s = 128; s > 0; s >>= 1) { if (t < s) red[t] += red[t + s]; __syncthreads(); }
    if (t == 0) bsum[b] = red[0];
}

__global__ void scan2_kernel(const int* __restrict__ bsum, int* __restrict__ boff,
                             int* __restrict__ rowptr) {
    __shared__ int s[256];
    int t = threadIdx.x;
    int v = (t < NBLK) ? bsum[t] : 0;
    s[t] = v;
    __syncthreads();
    for (int d = 1; d < 256; d <<= 1) {
        int x = s[t];
        int a = (t >= d) ? s[t - d] : 0;
        __syncthreads();
        s[t] = x + a;
        __syncthreads();
    }
    if (t < NBLK) boff[t] = s[t] - v;
    if (t == NBLK - 1) rowptr[NN] = s[t];
}

__global__ void scan3_kernel(const int* __restrict__ deg, const int* __restrict__ boff,
                             int* __restrict__ rowptr) {
    __shared__ int s[256];
    int b = blockIdx.x, t = threadIdx.x;
    int idx = b * 256 + t;
    int v = (idx < NN) ? deg[idx] : 0;
    s[t] = v;
    __syncthreads();
    for (int d = 1; d < 256; d <<= 1) {
        int x = s[t];
        int a = (t >= d) ? s[t - d] : 0;
        __syncthreads();
        s[t] = x + a;
        __syncthreads();
    }
    if (idx < NN) rowptr[idx] = boff[b] + s[t] - v;
}

__global__ void scatter_kernel(const int* __restrict__ ei, int* __restrict__ cursor,
                               int* __restrict__ esrc) {
    int t = blockIdx.x * 256 + threadIdx.x;
    if (t >= ETOT) return;
    int s, d;
    if (t < NE) { s = ei[t]; d = ei[NE + t]; } else { s = d = t - NE; }
    int pos = atomicAdd(&cursor[d], 1);
    esrc[pos] = s;
}

// ---- graph boundaries from sorted batch: gstart[g] = first node of graph g ----
__global__ void gbound_kernel(const int* __restrict__ batch, int* __restrict__ gstart) {
    int n = blockIdx.x * 256 + threadIdx.x;
    if (n >= NN) return;
    int b = batch[n];
    int prev = (n == 0) ? -1 : batch[n - 1];
    for (int g = prev + 1; g <= b; ++g) gstart[g] = n;
    if (n == NN - 1)
        for (int g = b + 1; g <= NG; ++g) gstart[g] = NN;
}

// ---- fused per-dst aggregation: ONE WAVE PER NODE. ----
__global__ __launch_bounds__(256, 8) void agg_csr_kernel(
    const int* __restrict__ rowptr, const int* __restrict__ esrc,
    const float* __restrict__ alsrc, const float* __restrict__ aldst,
    const unsigned short* __restrict__ h, const float* __restrict__ bias,
    float* __restrict__ out) {
    int l = threadIdx.x & 63;
    int n = blockIdx.x * 4 + (threadIdx.x >> 6);   // NN % 4 == 0
    int hd = l >> 4;
    float ad = aldst[n * 4 + hd];
    float4 bv = *(const float4*)(bias + l * 4);
    int beg = rowptr[n], end = rowptr[n + 1];
    float a0 = 0.f, a1 = 0.f, a2 = 0.f, a3 = 0.f, den = 0.f;
#pragma unroll 4
    for (int e = beg; e < end; ++e) {
        int s = esrc[e];
        float wgt = __expf(lrelu(alsrc[s * 4 + hd] + ad));
        uint2 hv = *(const uint2*)(h + (size_t)s * 256 + l * 4);
        den += wgt;
        a0 = fmaf(wgt, bf2f((unsigned short)hv.x), a0);
        a1 = fmaf(wgt, bf2f((unsigned short)(hv.x >> 16)), a1);
        a2 = fmaf(wgt, bf2f((unsigned short)hv.y), a2);
        a3 = fmaf(wgt, bf2f((unsigned short)(hv.y >> 16)), a3);
    }
    float r = 1.f / (den + 1e-16f);
    *(float4*)(out + (size_t)n * 256 + l * 4) =
        make_float4(fmaf(a0, r, bv.x), fmaf(a1, r, bv.y),
                    fmaf(a2, r, bv.z), fmaf(a3, r, bv.w));
}

// ---- fused BN stats ----
__global__ void bn_stats_kernel(const float* __restrict__ x1, float* __restrict__ S,
                                float* __restrict__ S2) {
    int j = threadIdx.x, b = blockIdx.x;
    float s = 0.f, s2 = 0.f;
    for (int n = b; n < NN; n += gridDim.x) {
        float v = x1[(size_t)n * 256 + j];
        s += v;
        s2 = fmaf(v, v, s2);
    }
    atomicAdd(&S[j], s);
    atomicAdd(&S2[j], s2);
}

// ---- BN apply + relu -> xnext(bf16); per-node softmax stats m[n], rs[n]=1/sum.
// ONE WAVE PER NODE: no LDS, no barriers, no atomics. ----
__global__ __launch_bounds__(256, 8) void bn_apply_kernel(
    const float* __restrict__ x1, const float* __restrict__ S, const float* __restrict__ S2,
    const float* __restrict__ gamma, const float* __restrict__ beta,
    unsigned short* __restrict__ xnext, float* __restrict__ mrow, float* __restrict__ rsrow) {
    int l = threadIdx.x & 63;
    int n = blockIdx.x * 4 + (threadIdx.x >> 6);   // NN % 4 == 0
    int c = l * 4;
    float4 xv = *(const float4*)(x1 + (size_t)n * 256 + c);
    float4 s4 = *(const float4*)(S + c);
    float4 q4 = *(const float4*)(S2 + c);
    float4 g4 = *(const float4*)(gamma + c);
    float4 b4 = *(const float4*)(beta + c);
    float v[4];
    {
        float xs[4] = {xv.x, xv.y, xv.z, xv.w};
        float ss[4] = {s4.x, s4.y, s4.z, s4.w};
        float qs[4] = {q4.x, q4.y, q4.z, q4.w};
        float gs[4] = {g4.x, g4.y, g4.z, g4.w};
        float bs[4] = {b4.x, b4.y, b4.z, b4.w};
#pragma unroll
        for (int i = 0; i < 4; ++i) {
            float mu = ss[i] * (1.f / NN);
            float var = fmaxf(qs[i] * (1.f / NN) - mu * mu, 0.f);
            v[i] = fmaxf((xs[i] - mu) * rsqrtf(var + 1e-5f) * gs[i] + bs[i], 0.f);
        }
    }
    float m = fmaxf(fmaxf(v[0], v[1]), fmaxf(v[2], v[3]));
#pragma unroll
    for (int o = 1; o < 64; o <<= 1) m = fmaxf(m, __shfl_xor(m, o, 64));
    float e0 = __expf(v[0] - m), e1 = __expf(v[1] - m);
    float e2 = __expf(v[2] - m), e3 = __expf(v[3] - m);
    float sum = e0 + e1 + e2 + e3;
#pragma unroll
    for (int o = 1; o < 64; o <<= 1) sum += __shfl_xor(sum, o, 64);
    uint2 pk;
    pk.x = (unsigned int)f2bf(v[0]) | ((unsigned int)f2bf(v[1]) << 16);
    pk.y = (unsigned int)f2bf(v[2]) | ((unsigned int)f2bf(v[3]) << 16);
    *(uint2*)(xnext + (size_t)n * 256 + c) = pk;
    if (l == 0) { mrow[n] = m; rsrow[n] = 1.f / sum; }
}

// ---- graph pooling, NO atomics: block = (graph g, 64-channel slice).
// Recomputes v from f32 x1 with the identical BN formula. ----
__global__ __launch_bounds__(64) void pool_kernel(
    const float* __restrict__ x1, const float* __restrict__ S, const float* __restrict__ S2,
    const float* __restrict__ gamma, const float* __restrict__ beta,
    const float* __restrict__ mrow, const float* __restrict__ rsrow,
    const int* __restrict__ gstart, float* __restrict__ f) {
    int g = blockIdx.x;
    int j = blockIdx.y * 64 + threadIdx.x;
    float mu = S[j] * (1.f / NN);
    float var = fmaxf(S2[j] * (1.f / NN) - mu * mu, 0.f);
    float rq = rsqrtf(var + 1e-5f);
    float ga = gamma[j], be = beta[j];
    int beg = gstart[g], end = gstart[g + 1];
    float acc = 0.f;
#pragma unroll 4
    for (int n = beg; n < end; ++n) {
        float v = fmaxf((x1[(size_t)n * 256 + j] - mu) * rq * ga + be, 0.f);
        acc += __expf(v - mrow[n]) * rsrow[n];
    }
    f[g * 256 + j] += acc;
}

__global__ void mlp_kernel(const float* __restrict__ A, const float* __restrict__ W,
                           const float* __restrict__ b, float* __restrict__ out, int do_relu) {
    int i = blockIdx.x, j = threadIdx.x;
    __shared__ float row[256];
    row[j] = A[i * 256 + j];
    __syncthreads();
    float acc = b[j];
#pragma unroll 8
    for (int k = 0; k < 256; ++k) acc = fmaf(row[k], W[k * 256 + j], acc);
    if (do_relu) acc = fmaxf(acc, 0.f);
    out[i * 256 + j] = acc;
}

extern "C" void kernel_launch(void* const* d_in, const int* in_sizes, int n_in,
                              void* d_out, int out_size, void* d_ws, size_t ws_size,
                              hipStream_t stream) {
    const float* x0     = (const float*)d_in[0];
    const int*   ei     = (const int*)d_in[1];
    const int*   batch  = (const int*)d_in[2];
    const float* W0     = (const float*)d_in[3];
    const float* asrc0  = (const float*)d_in[4];
    const float* adst0  = (const float*)d_in[5];
    const float* bias0  = (const float*)d_in[6];
    const float* W12    = (const float*)d_in[7];
    const float* asrc12 = (const float*)d_in[8];
    const float* adst12 = (const float*)d_in[9];
    const float* bias12 = (const float*)d_in[10];
    const float* gamma  = (const float*)d_in[11];
    const float* beta   = (const float*)d_in[12];
    const float* Wm1    = (const float*)d_in[13];
    const float* bm1    = (const float*)d_in[14];
    const float* Wm2    = (const float*)d_in[15];
    const float* bm2    = (const float*)d_in[16];
    float* out = (float*)d_out;

    float* ws = (float*)d_ws;
    const size_t NODE_F = (size_t)NN * 256;
    unsigned short* h16  = (unsigned short*)ws;                 // NODE_F ushorts
    float*          x1   = ws + NODE_F / 2;                     // NODE_F floats
    unsigned short* xb16 = (unsigned short*)(x1 + NODE_F);      // NODE_F ushorts
    unsigned short* wt   = xb16 + NODE_F;                       // 2*65536 ushorts
    float* alsrc  = (float*)(wt + 2 * 65536);
    float* aldst  = alsrc + (size_t)NN * 4;
    float* S      = aldst + (size_t)NN * 4;
    float* S2     = S + 256;
    float* fpool  = S2 + 256;
    float* g_buf  = fpool + 65536;
    float* mrow   = g_buf + 65536;
    float* rsrow  = mrow + NN;
    int*   deg    = (int*)(rsrow + NN);
    int*   rowptr = deg + NN + 1;
    int*   cursor = rowptr + NN + 1;
    int*   bsum   = cursor + NN + 1;
    int*   boff   = bsum + NBLK + 1;
    int*   gstart = boff + NBLK + 1;
    int*   esrc   = gstart + NG + 1;

    // CSR by dst (shared by all layers)
    hipMemsetAsync(deg, 0, (NN + 1) * sizeof(int), stream);
    hist_kernel<<<(ETOT + 255) / 256, 256, 0, stream>>>(ei, deg);
    scan1_kernel<<<NBLK, 256, 0, stream>>>(deg, bsum);
    scan2_kernel<<<1, 256, 0, stream>>>(bsum, boff, rowptr);
    scan3_kernel<<<NBLK, 256, 0, stream>>>(deg, boff, rowptr);
    hipMemcpyAsync(cursor, rowptr, (NN + 1) * sizeof(int), hipMemcpyDeviceToDevice, stream);
    scatter_kernel<<<(ETOT + 255) / 256, 256, 0, stream>>>(ei, cursor, esrc);

    // graph boundaries (batch is sorted)
    gbound_kernel<<<(NN + 255) / 256, 256, 0, stream>>>(batch, gstart);

    // bf16-transposed weights for layers 1,2
    wt_kernel<<<256, 256, 0, stream>>>(W12, wt);
    wt_kernel<<<256, 256, 0, stream>>>(W12 + 65536, wt + 65536);

    hipMemsetAsync(fpool, 0, 65536 * sizeof(float), stream);

    for (int l = 0; l < 3; ++l) {
        const float* as = (l == 0) ? asrc0 : asrc12 + (size_t)(l - 1) * 256;
        const float* ad = (l == 0) ? adst0 : adst12 + (size_t)(l - 1) * 256;
        const float* bs = (l == 0) ? bias0 : bias12 + (size_t)(l - 1) * 256;

        if (l == 0) {
            gemm_h_kernel<<<NN, 256, (9 + 256) * sizeof(float), stream>>>(
                x0, W0, as, ad, h16, alsrc, aldst, 9);
        } else {
            dim3 grid((NN + 127) / 128, 2);
            gemm_mfma_kernel<<<grid, 256, 0, stream>>>(
                xb16, wt + (size_t)(l - 1) * 65536, as, ad, h16, alsrc, aldst);
        }

        agg_csr_kernel<<<NN / 4, 256, 0, stream>>>(rowptr, esrc, alsrc, aldst, h16, bs, x1);

        hipMemsetAsync(S, 0, 512 * sizeof(float), stream);
        bn_stats_kernel<<<1024, 256, 0, stream>>>(x1, S, S2);

        bn_apply_kernel<<<NN / 4, 256, 0, stream>>>(
            x1, S, S2, gamma + l * 256, beta + l * 256, xb16, mrow, rsrow);

        pool_kernel<<<dim3(NG, 4), 64, 0, stream>>>(
            x1, S, S2, gamma + l * 256, beta + l * 256, mrow, rsrow, gstart, fpool);
    }

    mlp_kernel<<<256, 256, 0, stream>>>(fpool, Wm1, bm1, g_buf, 1);
    mlp_kernel<<<256, 256, 0, stream>>>(g_buf, Wm2, bm2, out, 0);
}